// Round 1
// baseline (8155.974 us; speedup 1.0000x reference)
//
#include <hip/hip_runtime.h>
#include <math.h>

// GCN forward: 3x GCNConv(H=8) + mean-pool + two tiny heads.
// out[0..N-1] = proba, out[N] = value.
//
// Per layer, using g = dis * (h @ W):
//   h_out[c] = relu( dis[c] * ( sum_{edges e: col=c} g[row_e]  +  g[c] ) + b )
// (self-loop term = g[c], since its norm is dis[c]^2 and msg = h'[c]*dis[c]^2.)

#define HBLK 256
static constexpr int HDIM = 8;

// ---- init: deg=1 (self loop), acc=0, mean=0 ----
__global__ void k_init(float* __restrict__ deg, float* __restrict__ acc,
                       float* __restrict__ mean_acc, int n, int accn) {
    int i = blockIdx.x * blockDim.x + threadIdx.x;
    if (i < accn) acc[i] = 0.0f;
    if (i < n) deg[i] = 1.0f;
    if (i < HDIM) mean_acc[i] = 0.0f;
}

// ---- degree scatter ----
__global__ void k_deg(const int* __restrict__ col, int E, float* __restrict__ deg) {
    int e = blockIdx.x * blockDim.x + threadIdx.x;
    if (e < E) atomicAdd(&deg[col[e]], 1.0f);
}

// ---- layer-1 projection: dis = rsqrt(deg) (stored in place), g = dis * (x @ W1) ----
__global__ void k_proj1(const float* __restrict__ x, const float* __restrict__ W1,
                        float* __restrict__ deg_dis, float* __restrict__ g, int n) {
    __shared__ float Ws[128 * HDIM];
    for (int t = threadIdx.x; t < 128 * HDIM; t += blockDim.x) Ws[t] = W1[t];
    __syncthreads();
    int i = blockIdx.x * blockDim.x + threadIdx.x;
    if (i >= n) return;
    const float4* xr = (const float4*)(x + (size_t)i * 128);
    float a[HDIM] = {0, 0, 0, 0, 0, 0, 0, 0};
#pragma unroll
    for (int k4 = 0; k4 < 32; ++k4) {
        float4 xv = xr[k4];
        const float* w = &Ws[k4 * 4 * HDIM];
#pragma unroll
        for (int j = 0; j < HDIM; ++j)
            a[j] += xv.x * w[j] + xv.y * w[HDIM + j] + xv.z * w[2 * HDIM + j] + xv.w * w[3 * HDIM + j];
    }
    float d = deg_dis[i];
    float di = d > 0.0f ? rsqrtf(d) : 0.0f;
    deg_dis[i] = di;
    float4* gp = (float4*)(g + (size_t)i * HDIM);
    gp[0] = make_float4(di * a[0], di * a[1], di * a[2], di * a[3]);
    gp[1] = make_float4(di * a[4], di * a[5], di * a[6], di * a[7]);
}

// ---- edge scatter: acc[col] += g[row] ----
__global__ void k_scatter(const int* __restrict__ row, const int* __restrict__ col,
                          const float* __restrict__ g, float* __restrict__ acc, int E) {
    int e = blockIdx.x * blockDim.x + threadIdx.x;
    if (e >= E) return;
    int r = row[e], c = col[e];
    const float4* gp = (const float4*)(g + (size_t)r * HDIM);
    float4 a = gp[0], b = gp[1];
    float* ap = acc + (size_t)c * HDIM;
    atomicAdd(ap + 0, a.x); atomicAdd(ap + 1, a.y);
    atomicAdd(ap + 2, a.z); atomicAdd(ap + 3, a.w);
    atomicAdd(ap + 4, b.x); atomicAdd(ap + 5, b.y);
    atomicAdd(ap + 6, b.z); atomicAdd(ap + 7, b.w);
}

// ---- mid finalize: h = relu(dis*(acc+g)+b); g_next = dis*(h@Wn); acc re-zeroed ----
__global__ void k_mid(const float* __restrict__ dis, float* __restrict__ acc,
                      float* __restrict__ g, const float* __restrict__ b,
                      const float* __restrict__ Wn, int n) {
    __shared__ float Ws[HDIM * HDIM];
    __shared__ float bs[HDIM];
    if (threadIdx.x < HDIM * HDIM) Ws[threadIdx.x] = Wn[threadIdx.x];
    if (threadIdx.x < HDIM) bs[threadIdx.x] = b[threadIdx.x];
    __syncthreads();
    int i = blockIdx.x * blockDim.x + threadIdx.x;
    if (i >= n) return;
    float di = dis[i];
    float4* ap = (float4*)(acc + (size_t)i * HDIM);
    float4* gp = (float4*)(g + (size_t)i * HDIM);
    float4 a0 = ap[0], a1 = ap[1], g0 = gp[0], g1 = gp[1];
    float h[HDIM];
    h[0] = fmaxf(di * (a0.x + g0.x) + bs[0], 0.0f);
    h[1] = fmaxf(di * (a0.y + g0.y) + bs[1], 0.0f);
    h[2] = fmaxf(di * (a0.z + g0.z) + bs[2], 0.0f);
    h[3] = fmaxf(di * (a0.w + g0.w) + bs[3], 0.0f);
    h[4] = fmaxf(di * (a1.x + g1.x) + bs[4], 0.0f);
    h[5] = fmaxf(di * (a1.y + g1.y) + bs[5], 0.0f);
    h[6] = fmaxf(di * (a1.z + g1.z) + bs[6], 0.0f);
    h[7] = fmaxf(di * (a1.w + g1.w) + bs[7], 0.0f);
    // re-zero acc for the next scatter pass
    ap[0] = make_float4(0, 0, 0, 0);
    ap[1] = make_float4(0, 0, 0, 0);
    float gn[HDIM];
#pragma unroll
    for (int j = 0; j < HDIM; ++j) {
        float s = 0.0f;
#pragma unroll
        for (int k = 0; k < HDIM; ++k) s += h[k] * Ws[k * HDIM + j];
        gn[j] = di * s;
    }
    gp[0] = make_float4(gn[0], gn[1], gn[2], gn[3]);
    gp[1] = make_float4(gn[4], gn[5], gn[6], gn[7]);
}

// ---- final: h3, proba to out, block-reduced sum(h3) into mean_acc ----
__global__ void k_final(const float* __restrict__ dis, const float* __restrict__ acc,
                        const float* __restrict__ g, const float* __restrict__ b3,
                        const float* __restrict__ Wp, const float* __restrict__ bp,
                        float* __restrict__ out, float* __restrict__ mean_acc, int n) {
    int i = blockIdx.x * blockDim.x + threadIdx.x;
    float h[HDIM] = {0, 0, 0, 0, 0, 0, 0, 0};
    if (i < n) {
        float di = dis[i];
        const float4* ap = (const float4*)(acc + (size_t)i * HDIM);
        const float4* gp = (const float4*)(g + (size_t)i * HDIM);
        float4 a0 = ap[0], a1 = ap[1], g0 = gp[0], g1 = gp[1];
        h[0] = fmaxf(di * (a0.x + g0.x) + b3[0], 0.0f);
        h[1] = fmaxf(di * (a0.y + g0.y) + b3[1], 0.0f);
        h[2] = fmaxf(di * (a0.z + g0.z) + b3[2], 0.0f);
        h[3] = fmaxf(di * (a0.w + g0.w) + b3[3], 0.0f);
        h[4] = fmaxf(di * (a1.x + g1.x) + b3[4], 0.0f);
        h[5] = fmaxf(di * (a1.y + g1.y) + b3[5], 0.0f);
        h[6] = fmaxf(di * (a1.z + g1.z) + b3[6], 0.0f);
        h[7] = fmaxf(di * (a1.w + g1.w) + b3[7], 0.0f);
        float p = bp[0];
#pragma unroll
        for (int j = 0; j < HDIM; ++j) p += h[j] * Wp[j];
        out[i] = p;
    }
    // wave reduction of h into mean accumulator (all threads participate)
#pragma unroll
    for (int j = 0; j < HDIM; ++j) {
        float s = h[j];
#pragma unroll
        for (int off = 32; off > 0; off >>= 1) s += __shfl_down(s, off);
        if ((threadIdx.x & 63) == 0) atomicAdd(&mean_acc[j], s);
    }
}

// ---- value head ----
__global__ void k_value(const float* __restrict__ mean_acc, const float* __restrict__ Wv,
                        const float* __restrict__ bv, float* __restrict__ out, int n) {
    if (threadIdx.x == 0 && blockIdx.x == 0) {
        float v = bv[0];
        float inv_n = 1.0f / (float)n;
#pragma unroll
        for (int j = 0; j < HDIM; ++j) v += (mean_acc[j] * inv_n) * Wv[j];
        out[n] = v;
    }
}

extern "C" void kernel_launch(void* const* d_in, const int* in_sizes, int n_in,
                              void* d_out, int out_size, void* d_ws, size_t ws_size,
                              hipStream_t stream) {
    const float* x  = (const float*)d_in[0];
    const int*   ei = (const int*)d_in[1];
    const float* W1 = (const float*)d_in[2];
    const float* b1 = (const float*)d_in[3];
    const float* W2 = (const float*)d_in[4];
    const float* b2 = (const float*)d_in[5];
    const float* W3 = (const float*)d_in[6];
    const float* b3 = (const float*)d_in[7];
    const float* Wp = (const float*)d_in[8];
    const float* bp = (const float*)d_in[9];
    const float* Wv = (const float*)d_in[10];
    const float* bv = (const float*)d_in[11];

    const int n = in_sizes[0] / 128;
    const int E = in_sizes[1] / 2;
    const int* row = ei;       // edge_index[0] = source
    const int* col = ei + E;   // edge_index[1] = target

    float* ws = (float*)d_ws;
    float* deg_dis  = ws;                       // [n]   deg, then dis in place
    float* g        = ws + (size_t)n;           // [n*8]
    float* acc      = ws + (size_t)n * 9;       // [n*8]
    float* mean_acc = ws + (size_t)n * 17;      // [8]
    float* out      = (float*)d_out;

    const int accn = n * HDIM;
    dim3 blk(HBLK);
    dim3 grid_init((accn + HBLK - 1) / HBLK);
    dim3 grid_n((n + HBLK - 1) / HBLK);
    dim3 grid_e((E + HBLK - 1) / HBLK);

    k_init<<<grid_init, blk, 0, stream>>>(deg_dis, acc, mean_acc, n, accn);
    k_deg<<<grid_e, blk, 0, stream>>>(col, E, deg_dis);
    k_proj1<<<grid_n, blk, 0, stream>>>(x, W1, deg_dis, g, n);

    // layer 1
    k_scatter<<<grid_e, blk, 0, stream>>>(row, col, g, acc, E);
    k_mid<<<grid_n, blk, 0, stream>>>(deg_dis, acc, g, b1, W2, n);
    // layer 2
    k_scatter<<<grid_e, blk, 0, stream>>>(row, col, g, acc, E);
    k_mid<<<grid_n, blk, 0, stream>>>(deg_dis, acc, g, b2, W3, n);
    // layer 3
    k_scatter<<<grid_e, blk, 0, stream>>>(row, col, g, acc, E);
    k_final<<<grid_n, blk, 0, stream>>>(deg_dis, acc, g, b3, Wp, bp, out, mean_acc, n);
    k_value<<<dim3(1), dim3(64), 0, stream>>>(mean_acc, Wv, bv, out, n);
}

// Round 2
// 1473.597 us; speedup vs baseline: 5.5347x; 5.5347x over previous
//
#include <hip/hip_runtime.h>
#include <math.h>

// GCN forward, CSR-gather formulation (no f32 atomics).
// Per layer, with g = dis * (h @ W):
//   h_out[c] = relu( dis[c] * ( sum_{e: col=c} g[row_e] + g[c] ) + b )
// CSR built per call: cnt -> exclusive scan (off) -> placement (perm).
// out[0..N-1] = proba, out[N] = value.

#define HBLK 256
static constexpr int HDIM = 8;

// ---- zero cnt + mean ----
__global__ void k_zero(int* __restrict__ cnt, float* __restrict__ mean_acc, int n) {
    int i = blockIdx.x * blockDim.x + threadIdx.x;
    if (i < n) cnt[i] = 0;
    if (i < HDIM) mean_acc[i] = 0.0f;
}

// ---- incoming-degree count (int atomics) ----
__global__ void k_count(const int* __restrict__ col, int E, int* __restrict__ cnt) {
    int e = blockIdx.x * blockDim.x + threadIdx.x;
    if (e < E) atomicAdd(&cnt[col[e]], 1);
}

// ---- single-block exclusive scan: off, cursor copies; dis = rsqrt(cnt+1) ----
__global__ void k_scan(const int* __restrict__ cnt, int* __restrict__ off,
                       int* __restrict__ cursor, float* __restrict__ dis, int n) {
    __shared__ int ts[1024];
    int t = threadIdx.x;
    int chunk = (n + 1023) >> 10;
    int s0 = t * chunk;
    int s1 = s0 + chunk; if (s1 > n) s1 = n;
    if (s0 > n) s0 = n;
    int sum = 0;
    for (int i = s0; i < s1; ++i) sum += cnt[i];
    ts[t] = sum;
    __syncthreads();
    // Hillis-Steele inclusive scan in LDS
    for (int d = 1; d < 1024; d <<= 1) {
        int v = ts[t];
        int add = (t >= d) ? ts[t - d] : 0;
        __syncthreads();
        ts[t] = v + add;
        __syncthreads();
    }
    if (t == 1023) off[n] = ts[1023];
    int run = (t == 0) ? 0 : ts[t - 1];
    for (int i = s0; i < s1; ++i) {
        int c = cnt[i];
        off[i] = run;
        cursor[i] = run;
        dis[i] = rsqrtf((float)(c + 1));   // +1 self loop; always > 0
        run += c;
    }
}

// ---- CSR placement: perm[pos] = row  (int atomics on 100k cursors) ----
__global__ void k_build(const int* __restrict__ row, const int* __restrict__ col,
                        int* __restrict__ cursor, int* __restrict__ perm, int E) {
    int e = blockIdx.x * blockDim.x + threadIdx.x;
    if (e >= E) return;
    int pos = atomicAdd(&cursor[col[e]], 1);
    perm[pos] = row[e];
}

// ---- layer-1 projection: g = dis * (x @ W1) ----
__global__ void k_proj1(const float* __restrict__ x, const float* __restrict__ W1,
                        const float* __restrict__ dis, float* __restrict__ g, int n) {
    __shared__ float Ws[128 * HDIM];
    for (int t = threadIdx.x; t < 128 * HDIM; t += blockDim.x) Ws[t] = W1[t];
    __syncthreads();
    int i = blockIdx.x * blockDim.x + threadIdx.x;
    if (i >= n) return;
    const float4* xr = (const float4*)(x + (size_t)i * 128);
    float a[HDIM] = {0, 0, 0, 0, 0, 0, 0, 0};
#pragma unroll
    for (int k4 = 0; k4 < 32; ++k4) {
        float4 xv = xr[k4];
        const float* w = &Ws[k4 * 4 * HDIM];
#pragma unroll
        for (int j = 0; j < HDIM; ++j)
            a[j] += xv.x * w[j] + xv.y * w[HDIM + j] + xv.z * w[2 * HDIM + j] + xv.w * w[3 * HDIM + j];
    }
    float di = dis[i];
    float4* gp = (float4*)(g + (size_t)i * HDIM);
    gp[0] = make_float4(di * a[0], di * a[1], di * a[2], di * a[3]);
    gp[1] = make_float4(di * a[4], di * a[5], di * a[6], di * a[7]);
}

// ---- fused layer: gather-aggregate + relu + next projection ----
__global__ void k_layer(const int* __restrict__ off, const int* __restrict__ perm,
                        const float* __restrict__ g_in, float* __restrict__ g_out,
                        const float* __restrict__ dis, const float* __restrict__ b,
                        const float* __restrict__ Wn, int n) {
    __shared__ float Ws[HDIM * HDIM];
    __shared__ float bs[HDIM];
    if (threadIdx.x < HDIM * HDIM) Ws[threadIdx.x] = Wn[threadIdx.x];
    if (threadIdx.x < HDIM) bs[threadIdx.x] = b[threadIdx.x];
    __syncthreads();
    int i = blockIdx.x * blockDim.x + threadIdx.x;
    if (i >= n) return;
    const float4* g4 = (const float4*)g_in;
    float4 s0 = g4[(size_t)i * 2], s1 = g4[(size_t)i * 2 + 1];  // self-loop term
    float a0 = s0.x, a1 = s0.y, a2 = s0.z, a3 = s0.w;
    float a4 = s1.x, a5 = s1.y, a6 = s1.z, a7 = s1.w;
    int s = off[i], e2 = off[i + 1];
    for (int p = s; p < e2; ++p) {
        int r = perm[p];
        float4 u = g4[(size_t)r * 2], v = g4[(size_t)r * 2 + 1];
        a0 += u.x; a1 += u.y; a2 += u.z; a3 += u.w;
        a4 += v.x; a5 += v.y; a6 += v.z; a7 += v.w;
    }
    float di = dis[i];
    float h[HDIM];
    h[0] = fmaxf(di * a0 + bs[0], 0.0f);
    h[1] = fmaxf(di * a1 + bs[1], 0.0f);
    h[2] = fmaxf(di * a2 + bs[2], 0.0f);
    h[3] = fmaxf(di * a3 + bs[3], 0.0f);
    h[4] = fmaxf(di * a4 + bs[4], 0.0f);
    h[5] = fmaxf(di * a5 + bs[5], 0.0f);
    h[6] = fmaxf(di * a6 + bs[6], 0.0f);
    h[7] = fmaxf(di * a7 + bs[7], 0.0f);
    float gn[HDIM];
#pragma unroll
    for (int j = 0; j < HDIM; ++j) {
        float sj = 0.0f;
#pragma unroll
        for (int k = 0; k < HDIM; ++k) sj += h[k] * Ws[k * HDIM + j];
        gn[j] = di * sj;
    }
    float4* gp = (float4*)(g_out + (size_t)i * HDIM);
    gp[0] = make_float4(gn[0], gn[1], gn[2], gn[3]);
    gp[1] = make_float4(gn[4], gn[5], gn[6], gn[7]);
}

// ---- fused final layer: gather + relu + proba head + mean reduce ----
__global__ void k_layer3(const int* __restrict__ off, const int* __restrict__ perm,
                         const float* __restrict__ g_in, const float* __restrict__ dis,
                         const float* __restrict__ b3, const float* __restrict__ Wp,
                         const float* __restrict__ bp, float* __restrict__ out,
                         float* __restrict__ mean_acc, int n) {
    int i = blockIdx.x * blockDim.x + threadIdx.x;
    float h[HDIM] = {0, 0, 0, 0, 0, 0, 0, 0};
    if (i < n) {
        const float4* g4 = (const float4*)g_in;
        float4 s0 = g4[(size_t)i * 2], s1 = g4[(size_t)i * 2 + 1];
        float a0 = s0.x, a1 = s0.y, a2 = s0.z, a3 = s0.w;
        float a4 = s1.x, a5 = s1.y, a6 = s1.z, a7 = s1.w;
        int s = off[i], e2 = off[i + 1];
        for (int p = s; p < e2; ++p) {
            int r = perm[p];
            float4 u = g4[(size_t)r * 2], v = g4[(size_t)r * 2 + 1];
            a0 += u.x; a1 += u.y; a2 += u.z; a3 += u.w;
            a4 += v.x; a5 += v.y; a6 += v.z; a7 += v.w;
        }
        float di = dis[i];
        h[0] = fmaxf(di * a0 + b3[0], 0.0f);
        h[1] = fmaxf(di * a1 + b3[1], 0.0f);
        h[2] = fmaxf(di * a2 + b3[2], 0.0f);
        h[3] = fmaxf(di * a3 + b3[3], 0.0f);
        h[4] = fmaxf(di * a4 + b3[4], 0.0f);
        h[5] = fmaxf(di * a5 + b3[5], 0.0f);
        h[6] = fmaxf(di * a6 + b3[6], 0.0f);
        h[7] = fmaxf(di * a7 + b3[7], 0.0f);
        float p = bp[0];
#pragma unroll
        for (int j = 0; j < HDIM; ++j) p += h[j] * Wp[j];
        out[i] = p;
    }
#pragma unroll
    for (int j = 0; j < HDIM; ++j) {
        float sj = h[j];
#pragma unroll
        for (int o = 32; o > 0; o >>= 1) sj += __shfl_down(sj, o);
        if ((threadIdx.x & 63) == 0) atomicAdd(&mean_acc[j], sj);
    }
}

// ---- value head ----
__global__ void k_value(const float* __restrict__ mean_acc, const float* __restrict__ Wv,
                        const float* __restrict__ bv, float* __restrict__ out, int n) {
    if (threadIdx.x == 0 && blockIdx.x == 0) {
        float v = bv[0];
        float inv_n = 1.0f / (float)n;
#pragma unroll
        for (int j = 0; j < HDIM; ++j) v += (mean_acc[j] * inv_n) * Wv[j];
        out[n] = v;
    }
}

extern "C" void kernel_launch(void* const* d_in, const int* in_sizes, int n_in,
                              void* d_out, int out_size, void* d_ws, size_t ws_size,
                              hipStream_t stream) {
    const float* x  = (const float*)d_in[0];
    const int*   ei = (const int*)d_in[1];
    const float* W1 = (const float*)d_in[2];
    const float* b1 = (const float*)d_in[3];
    const float* W2 = (const float*)d_in[4];
    const float* b2 = (const float*)d_in[5];
    const float* W3 = (const float*)d_in[6];
    const float* b3 = (const float*)d_in[7];
    const float* Wp = (const float*)d_in[8];
    const float* bp = (const float*)d_in[9];
    const float* Wv = (const float*)d_in[10];
    const float* bv = (const float*)d_in[11];

    const int n = in_sizes[0] / 128;
    const int E = in_sizes[1] / 2;
    const int* row = ei;       // edge_index[0] = source
    const int* col = ei + E;   // edge_index[1] = target

    // workspace layout (4-byte units; g buffers kept 16B-aligned via off padding)
    int*   cnt    = (int*)d_ws;                 // n
    int*   off    = cnt + n;                    // n+16 (padded)
    int*   cursor = off + n + 16;               // n
    int*   perm   = cursor + n;                 // E
    float* dis    = (float*)(perm + E);         // n
    float* g_a    = dis + n;                    // n*8
    float* g_b    = g_a + (size_t)n * HDIM;     // n*8
    float* mean_acc = g_b + (size_t)n * HDIM;   // 8

    dim3 blk(HBLK);
    dim3 grid_n((n + HBLK - 1) / HBLK);
    dim3 grid_e((E + HBLK - 1) / HBLK);

    k_zero <<<grid_n, blk, 0, stream>>>(cnt, mean_acc, n);
    k_count<<<grid_e, blk, 0, stream>>>(col, E, cnt);
    k_scan <<<dim3(1), dim3(1024), 0, stream>>>(cnt, off, cursor, dis, n);
    k_build<<<grid_e, blk, 0, stream>>>(row, col, cursor, perm, E);
    k_proj1<<<grid_n, blk, 0, stream>>>(x, W1, dis, g_a, n);

    k_layer<<<grid_n, blk, 0, stream>>>(off, perm, g_a, g_b, dis, b1, W2, n);
    k_layer<<<grid_n, blk, 0, stream>>>(off, perm, g_b, g_a, dis, b2, W3, n);
    k_layer3<<<grid_n, blk, 0, stream>>>(off, perm, g_a, dis, b3, Wp, bp,
                                         (float*)d_out, mean_acc, n);
    k_value<<<dim3(1), dim3(64), 0, stream>>>(mean_acc, Wv, bv, (float*)d_out, n);
}

// Round 3
// 1239.648 us; speedup vs baseline: 6.5793x; 1.1887x over previous
//
#include <hip/hip_runtime.h>
#include <math.h>

// GCN forward, bucket-multisplit + LDS aggregation (no per-edge global atomics
// on hot paths, no exact CSR).
// Buckets: destination blocks of 256 nodes (NBUCK = ceil(n/256) = 391).
// bedge[p] packs (row << 8) | (col & 255), grouped by bucket.
// Per layer, with g = dis * (h @ W):
//   h_out[c] = relu( dis[c] * ( sum_{e: col=c} g[row_e] + g[c] ) + b )
// out[0..N-1] = proba, out[N] = value.

static constexpr int HDIM = 8;
#define EPB 16              // edges per thread in bucketing kernels (4096/wg)
#define MAXBUCK 512

// ---- zero bucket histogram + mean accumulator ----
__global__ void k_zero(int* __restrict__ bhist, float* __restrict__ mean_acc, int nbuck) {
    int t = threadIdx.x;
    if (t < nbuck) bhist[t] = 0;
    if (t < HDIM) mean_acc[t] = 0.0f;
}

// ---- per-bucket histogram (LDS-staged, 391 global atomics per wg) ----
__global__ void k_bhist(const int* __restrict__ col, int E, int nbuck,
                        int* __restrict__ bhist) {
    __shared__ int lcnt[MAXBUCK];
    for (int b = threadIdx.x; b < nbuck; b += 256) lcnt[b] = 0;
    __syncthreads();
    int base = blockIdx.x * (256 * EPB);
#pragma unroll
    for (int k = 0; k < EPB; ++k) {
        int e = base + k * 256 + threadIdx.x;
        if (e < E) atomicAdd(&lcnt[col[e] >> 8], 1);
    }
    __syncthreads();
    for (int b = threadIdx.x; b < nbuck; b += 256) {
        int c = lcnt[b];
        if (c) atomicAdd(&bhist[b], c);
    }
}

// ---- scan bucket counts -> bbase[0..nbuck], init bcur ----
__global__ void k_bscan(const int* __restrict__ bhist, int nbuck,
                        int* __restrict__ bbase, int* __restrict__ bcur) {
    __shared__ int ts[MAXBUCK];
    int t = threadIdx.x;
    ts[t] = (t < nbuck) ? bhist[t] : 0;
    __syncthreads();
    for (int d = 1; d < MAXBUCK; d <<= 1) {
        int v = ts[t];
        int add = (t >= d) ? ts[t - d] : 0;
        __syncthreads();
        ts[t] = v + add;
        __syncthreads();
    }
    int ex = (t == 0) ? 0 : ts[t - 1];
    if (t < nbuck) { bbase[t] = ex; bcur[t] = ex; }
    if (t == nbuck) bbase[t] = ts[nbuck - 1];
}

// ---- multisplit scatter: bedge grouped by bucket, coalesced-ish writes ----
__global__ void k_bucket(const int* __restrict__ row, const int* __restrict__ col,
                         int E, int nbuck, int* __restrict__ bcur,
                         unsigned* __restrict__ bedge) {
    __shared__ int lcnt[MAXBUCK];
    __shared__ int lbase[MAXBUCK];
    for (int b = threadIdx.x; b < nbuck; b += 256) lcnt[b] = 0;
    __syncthreads();
    int base = blockIdx.x * (256 * EPB);
    int myb[EPB], myrank[EPB];
    unsigned myv[EPB];
#pragma unroll
    for (int k = 0; k < EPB; ++k) {
        int e = base + k * 256 + threadIdx.x;
        if (e < E) {
            int c = col[e];
            int b = c >> 8;
            myb[k] = b;
            myrank[k] = atomicAdd(&lcnt[b], 1);
            myv[k] = ((unsigned)row[e] << 8) | (unsigned)(c & 255);
        } else myb[k] = -1;
    }
    __syncthreads();
    for (int b = threadIdx.x; b < nbuck; b += 256) {
        int c = lcnt[b];
        lbase[b] = c ? atomicAdd(&bcur[b], c) : 0;
    }
    __syncthreads();
#pragma unroll
    for (int k = 0; k < EPB; ++k)
        if (myb[k] >= 0) bedge[lbase[myb[k]] + myrank[k]] = myv[k];
}

// ---- fused: per-bucket degree (LDS) -> dis; g = dis * (x @ W1) ----
__global__ void k_projdeg(const int* __restrict__ bbase, const unsigned* __restrict__ bedge,
                          const float* __restrict__ x, const float* __restrict__ W1,
                          float* __restrict__ dis, float* __restrict__ g, int n) {
    __shared__ int lcnt[256];
    __shared__ float Ws[128 * HDIM];
    int t = threadIdx.x;
    lcnt[t] = 0;
    for (int q = t; q < 128 * HDIM; q += 256) Ws[q] = W1[q];
    __syncthreads();
    int b = blockIdx.x;
    int s = bbase[b], e2 = bbase[b + 1];
    for (int p = s + t; p < e2; p += 256) atomicAdd(&lcnt[bedge[p] & 255], 1);
    __syncthreads();
    int i = (b << 8) + t;
    if (i >= n) return;
    float di = rsqrtf((float)(lcnt[t] + 1));   // +1 self loop
    dis[i] = di;
    const float4* xr = (const float4*)(x + (size_t)i * 128);
    float a[HDIM] = {0, 0, 0, 0, 0, 0, 0, 0};
#pragma unroll
    for (int k4 = 0; k4 < 32; ++k4) {
        float4 xv = xr[k4];
        const float* w = &Ws[k4 * 4 * HDIM];
#pragma unroll
        for (int j = 0; j < HDIM; ++j)
            a[j] += xv.x * w[j] + xv.y * w[HDIM + j] + xv.z * w[2 * HDIM + j] + xv.w * w[3 * HDIM + j];
    }
    float4* gp = (float4*)(g + (size_t)i * HDIM);
    gp[0] = make_float4(di * a[0], di * a[1], di * a[2], di * a[3]);
    gp[1] = make_float4(di * a[4], di * a[5], di * a[6], di * a[7]);
}

// ---- fused layer: LDS-atomic aggregate + relu + next projection ----
__global__ void k_layer_b(const int* __restrict__ bbase, const unsigned* __restrict__ bedge,
                          const float* __restrict__ g_in, float* __restrict__ g_out,
                          const float* __restrict__ dis, const float* __restrict__ bias,
                          const float* __restrict__ Wn, int n) {
    __shared__ float acc[256 * 9];   // stride 9 -> banks spread
    __shared__ float Ws[HDIM * HDIM];
    __shared__ float bs[HDIM];
    int t = threadIdx.x;
    if (t < HDIM * HDIM) Ws[t] = Wn[t];
    if (t < HDIM) bs[t] = bias[t];
    for (int q = t; q < 256 * 9; q += 256) acc[q] = 0.0f;
    __syncthreads();
    int b = blockIdx.x;
    int s = bbase[b], e2 = bbase[b + 1];
    const float4* g4 = (const float4*)g_in;
    for (int p = s + t; p < e2; p += 256) {
        unsigned v = bedge[p];
        int r = (int)(v >> 8), lc = (int)(v & 255);
        float4 u = g4[(size_t)r * 2], w = g4[(size_t)r * 2 + 1];
        float* a = &acc[lc * 9];
        atomicAdd(a + 0, u.x); atomicAdd(a + 1, u.y);
        atomicAdd(a + 2, u.z); atomicAdd(a + 3, u.w);
        atomicAdd(a + 4, w.x); atomicAdd(a + 5, w.y);
        atomicAdd(a + 6, w.z); atomicAdd(a + 7, w.w);
    }
    __syncthreads();
    int i = (b << 8) + t;
    if (i >= n) return;
    float di = dis[i];
    float4 s0 = g4[(size_t)i * 2], s1 = g4[(size_t)i * 2 + 1];
    const float* a = &acc[t * 9];
    float h[HDIM];
    h[0] = fmaxf(di * (a[0] + s0.x) + bs[0], 0.0f);
    h[1] = fmaxf(di * (a[1] + s0.y) + bs[1], 0.0f);
    h[2] = fmaxf(di * (a[2] + s0.z) + bs[2], 0.0f);
    h[3] = fmaxf(di * (a[3] + s0.w) + bs[3], 0.0f);
    h[4] = fmaxf(di * (a[4] + s1.x) + bs[4], 0.0f);
    h[5] = fmaxf(di * (a[5] + s1.y) + bs[5], 0.0f);
    h[6] = fmaxf(di * (a[6] + s1.z) + bs[6], 0.0f);
    h[7] = fmaxf(di * (a[7] + s1.w) + bs[7], 0.0f);
    float gn[HDIM];
#pragma unroll
    for (int j = 0; j < HDIM; ++j) {
        float sj = 0.0f;
#pragma unroll
        for (int k = 0; k < HDIM; ++k) sj += h[k] * Ws[k * HDIM + j];
        gn[j] = di * sj;
    }
    float4* gp = (float4*)(g_out + (size_t)i * HDIM);
    gp[0] = make_float4(gn[0], gn[1], gn[2], gn[3]);
    gp[1] = make_float4(gn[4], gn[5], gn[6], gn[7]);
}

// ---- final layer: aggregate + relu + proba head + mean reduce ----
__global__ void k_layer3_b(const int* __restrict__ bbase, const unsigned* __restrict__ bedge,
                           const float* __restrict__ g_in, const float* __restrict__ dis,
                           const float* __restrict__ b3, const float* __restrict__ Wp,
                           const float* __restrict__ bp, float* __restrict__ out,
                           float* __restrict__ mean_acc, int n) {
    __shared__ float acc[256 * 9];
    int t = threadIdx.x;
    for (int q = t; q < 256 * 9; q += 256) acc[q] = 0.0f;
    __syncthreads();
    int b = blockIdx.x;
    int s = bbase[b], e2 = bbase[b + 1];
    const float4* g4 = (const float4*)g_in;
    for (int p = s + t; p < e2; p += 256) {
        unsigned v = bedge[p];
        int r = (int)(v >> 8), lc = (int)(v & 255);
        float4 u = g4[(size_t)r * 2], w = g4[(size_t)r * 2 + 1];
        float* a = &acc[lc * 9];
        atomicAdd(a + 0, u.x); atomicAdd(a + 1, u.y);
        atomicAdd(a + 2, u.z); atomicAdd(a + 3, u.w);
        atomicAdd(a + 4, w.x); atomicAdd(a + 5, w.y);
        atomicAdd(a + 6, w.z); atomicAdd(a + 7, w.w);
    }
    __syncthreads();
    int i = (b << 8) + t;
    float h[HDIM] = {0, 0, 0, 0, 0, 0, 0, 0};
    if (i < n) {
        float di = dis[i];
        float4 s0 = g4[(size_t)i * 2], s1 = g4[(size_t)i * 2 + 1];
        const float* a = &acc[t * 9];
        h[0] = fmaxf(di * (a[0] + s0.x) + b3[0], 0.0f);
        h[1] = fmaxf(di * (a[1] + s0.y) + b3[1], 0.0f);
        h[2] = fmaxf(di * (a[2] + s0.z) + b3[2], 0.0f);
        h[3] = fmaxf(di * (a[3] + s0.w) + b3[3], 0.0f);
        h[4] = fmaxf(di * (a[4] + s1.x) + b3[4], 0.0f);
        h[5] = fmaxf(di * (a[5] + s1.y) + b3[5], 0.0f);
        h[6] = fmaxf(di * (a[6] + s1.z) + b3[6], 0.0f);
        h[7] = fmaxf(di * (a[7] + s1.w) + b3[7], 0.0f);
        float p = bp[0];
#pragma unroll
        for (int j = 0; j < HDIM; ++j) p += h[j] * Wp[j];
        out[i] = p;
    }
#pragma unroll
    for (int j = 0; j < HDIM; ++j) {
        float sj = h[j];
#pragma unroll
        for (int o = 32; o > 0; o >>= 1) sj += __shfl_down(sj, o);
        if ((threadIdx.x & 63) == 0) atomicAdd(&mean_acc[j], sj);
    }
}

// ---- value head ----
__global__ void k_value(const float* __restrict__ mean_acc, const float* __restrict__ Wv,
                        const float* __restrict__ bv, float* __restrict__ out, int n) {
    if (threadIdx.x == 0 && blockIdx.x == 0) {
        float v = bv[0];
        float inv_n = 1.0f / (float)n;
#pragma unroll
        for (int j = 0; j < HDIM; ++j) v += (mean_acc[j] * inv_n) * Wv[j];
        out[n] = v;
    }
}

extern "C" void kernel_launch(void* const* d_in, const int* in_sizes, int n_in,
                              void* d_out, int out_size, void* d_ws, size_t ws_size,
                              hipStream_t stream) {
    const float* x  = (const float*)d_in[0];
    const int*   ei = (const int*)d_in[1];
    const float* W1 = (const float*)d_in[2];
    const float* b1 = (const float*)d_in[3];
    const float* W2 = (const float*)d_in[4];
    const float* b2 = (const float*)d_in[5];
    const float* W3 = (const float*)d_in[6];
    const float* b3 = (const float*)d_in[7];
    const float* Wp = (const float*)d_in[8];
    const float* bp = (const float*)d_in[9];
    const float* Wv = (const float*)d_in[10];
    const float* bv = (const float*)d_in[11];

    const int n = in_sizes[0] / 128;
    const int E = in_sizes[1] / 2;
    const int* row = ei;       // edge_index[0] = source
    const int* col = ei + E;   // edge_index[1] = target
    const int nbuck = (n + 255) >> 8;

    // workspace layout (4-byte units)
    int*      bhist = (int*)d_ws;                      // [0,     512)
    int*      bbase = bhist + 1024;                    // [1024,  1544)
    int*      bcur  = bhist + 2048;                    // [2048,  2560)
    float*    mean_acc = (float*)(bhist + 3072);       // [3072,  3080)
    float*    dis   = (float*)(bhist + 4096);          // [4096,  4096+n)
    unsigned* bedge = (unsigned*)(dis + n);            // [.., +E)
    float*    g_a   = (float*)(bedge + E);             // 16B-aligned (4096+n+E ≡ 0 mod 4)
    float*    g_b   = g_a + (size_t)n * HDIM;

    dim3 blk(256);
    dim3 grid_e((E + 256 * EPB - 1) / (256 * EPB));
    dim3 grid_b(nbuck);

    k_zero  <<<dim3(1), dim3(512), 0, stream>>>(bhist, mean_acc, nbuck);
    k_bhist <<<grid_e, blk, 0, stream>>>(col, E, nbuck, bhist);
    k_bscan <<<dim3(1), dim3(MAXBUCK), 0, stream>>>(bhist, nbuck, bbase, bcur);
    k_bucket<<<grid_e, blk, 0, stream>>>(row, col, E, nbuck, bcur, bedge);
    k_projdeg<<<grid_b, blk, 0, stream>>>(bbase, bedge, x, W1, dis, g_a, n);

    k_layer_b<<<grid_b, blk, 0, stream>>>(bbase, bedge, g_a, g_b, dis, b1, W2, n);
    k_layer_b<<<grid_b, blk, 0, stream>>>(bbase, bedge, g_b, g_a, dis, b2, W3, n);
    k_layer3_b<<<grid_b, blk, 0, stream>>>(bbase, bedge, g_a, dis, b3, Wp, bp,
                                           (float*)d_out, mean_acc, n);
    k_value<<<dim3(1), dim3(64), 0, stream>>>(mean_acc, Wv, bv, (float*)d_out, n);
}

// Round 4
// 1142.310 us; speedup vs baseline: 7.1399x; 1.0852x over previous
//
#include <hip/hip_runtime.h>
#include <math.h>

// GCN forward. Bucket multisplit (dest blocks of 256 nodes), then per-layer:
//   k_agg   : grid (nbuck*KS) — slice of bucket's edges -> LDS acc -> partial
//   k_finish: thread/node — sum KS partials + self term, relu, next 8x8 proj
// No f32 global atomics anywhere (partials are plain coalesced stores).
// g = dis * (h @ W);  h_out[c] = relu( dis[c] * (sum_in g[row] + g[c]) + b )
// out[0..N-1] = proba, out[N] = value.

static constexpr int HDIM = 8;
#define EPB 16              // edges per thread in bucketing kernels
#define MAXBUCK 512

// ---- zero deg + bucket histogram + mean ----
__global__ void k_zero(int* __restrict__ deg, int* __restrict__ bhist,
                       float* __restrict__ mean_acc, int n, int nbuck) {
    int i = blockIdx.x * blockDim.x + threadIdx.x;
    if (i < n) deg[i] = 0;
    if (i < nbuck) bhist[i] = 0;
    if (i < HDIM) mean_acc[i] = 0.0f;
}

// ---- per-bucket histogram ----
__global__ void k_bhist(const int* __restrict__ col, int E, int nbuck,
                        int* __restrict__ bhist) {
    __shared__ int lcnt[MAXBUCK];
    for (int b = threadIdx.x; b < nbuck; b += 256) lcnt[b] = 0;
    __syncthreads();
    int base = blockIdx.x * (256 * EPB);
#pragma unroll
    for (int k = 0; k < EPB; ++k) {
        int e = base + k * 256 + threadIdx.x;
        if (e < E) atomicAdd(&lcnt[col[e] >> 8], 1);
    }
    __syncthreads();
    for (int b = threadIdx.x; b < nbuck; b += 256) {
        int c = lcnt[b];
        if (c) atomicAdd(&bhist[b], c);
    }
}

// ---- scan bucket counts -> bbase, init bcur ----
__global__ void k_bscan(const int* __restrict__ bhist, int nbuck,
                        int* __restrict__ bbase, int* __restrict__ bcur) {
    __shared__ int ts[MAXBUCK];
    int t = threadIdx.x;
    ts[t] = (t < nbuck) ? bhist[t] : 0;
    __syncthreads();
    for (int d = 1; d < MAXBUCK; d <<= 1) {
        int v = ts[t];
        int add = (t >= d) ? ts[t - d] : 0;
        __syncthreads();
        ts[t] = v + add;
        __syncthreads();
    }
    int ex = (t == 0) ? 0 : ts[t - 1];
    if (t < nbuck) { bbase[t] = ex; bcur[t] = ex; }
    if (t == nbuck) bbase[t] = ts[nbuck - 1];
}

// ---- multisplit scatter: bedge grouped by bucket ----
__global__ void k_bucket(const int* __restrict__ row, const int* __restrict__ col,
                         int E, int nbuck, int* __restrict__ bcur,
                         unsigned* __restrict__ bedge) {
    __shared__ int lcnt[MAXBUCK];
    __shared__ int lbase[MAXBUCK];
    for (int b = threadIdx.x; b < nbuck; b += 256) lcnt[b] = 0;
    __syncthreads();
    int base = blockIdx.x * (256 * EPB);
    int myb[EPB], myrank[EPB];
    unsigned myv[EPB];
#pragma unroll
    for (int k = 0; k < EPB; ++k) {
        int e = base + k * 256 + threadIdx.x;
        if (e < E) {
            int c = col[e];
            int b = c >> 8;
            myb[k] = b;
            myrank[k] = atomicAdd(&lcnt[b], 1);
            myv[k] = ((unsigned)row[e] << 8) | (unsigned)(c & 255);
        } else myb[k] = -1;
    }
    __syncthreads();
    for (int b = threadIdx.x; b < nbuck; b += 256) {
        int c = lcnt[b];
        lbase[b] = c ? atomicAdd(&bcur[b], c) : 0;
    }
    __syncthreads();
#pragma unroll
    for (int k = 0; k < EPB; ++k)
        if (myb[k] >= 0) bedge[lbase[myb[k]] + myrank[k]] = myv[k];
}

// ---- per-node degree from bedge, KS-split, LDS count + global int add ----
__global__ void k_deg2(const int* __restrict__ bbase, const unsigned* __restrict__ bedge,
                       int* __restrict__ deg, int KS, int n) {
    __shared__ int lcnt[256];
    int t = threadIdx.x;
    lcnt[t] = 0;
    __syncthreads();
    int b = blockIdx.x / KS, k = blockIdx.x % KS;
    int s = bbase[b], len = bbase[b + 1] - s;
    int lo = s + (int)((long long)len * k / KS);
    int hi = s + (int)((long long)len * (k + 1) / KS);
    for (int p = lo + t; p < hi; p += 256) atomicAdd(&lcnt[bedge[p] & 255], 1);
    __syncthreads();
    int i = (b << 8) + t;
    if (i < n && lcnt[t]) atomicAdd(&deg[i], lcnt[t]);
}

// ---- layer-1 projection, 4 threads/node: dis=rsqrt(deg+1); g = dis*(x@W1) ----
__global__ void k_proj1(const float* __restrict__ x, const float* __restrict__ W1,
                        const int* __restrict__ deg, float* __restrict__ dis,
                        float* __restrict__ g, int n) {
    __shared__ float Ws[32 * 36];          // chunk-padded: [c][j][r], stride 36
    const float4* Ws4 = (const float4*)Ws;
    for (int t = threadIdx.x; t < 1024; t += 256) {
        int c = t >> 5, rem = t & 31, j = rem >> 2, r = rem & 3;
        Ws[c * 36 + j * 4 + r] = W1[(c * 4 + r) * 8 + j];
    }
    __syncthreads();
    int t4 = blockIdx.x * blockDim.x + threadIdx.x;
    int i = t4 >> 2, sub = t4 & 3;
    if (i >= n) return;
    const float4* x4 = (const float4*)x;
    float a[HDIM] = {0, 0, 0, 0, 0, 0, 0, 0};
#pragma unroll
    for (int iter = 0; iter < 8; ++iter) {
        int c = iter * 4 + sub;
        float4 xv = x4[(size_t)i * 32 + c];
#pragma unroll
        for (int j = 0; j < HDIM; ++j) {
            float4 wv = Ws4[c * 9 + j];
            a[j] += xv.x * wv.x + xv.y * wv.y + xv.z * wv.z + xv.w * wv.w;
        }
    }
#pragma unroll
    for (int j = 0; j < HDIM; ++j) {
        a[j] += __shfl_xor(a[j], 1);
        a[j] += __shfl_xor(a[j], 2);
    }
    float di = rsqrtf((float)(deg[i] + 1));    // +1 self loop
    if (sub == 2) dis[i] = di;
    float4* gp = (float4*)(g + (size_t)i * HDIM);
    if (sub == 0) gp[0] = make_float4(di * a[0], di * a[1], di * a[2], di * a[3]);
    if (sub == 1) gp[1] = make_float4(di * a[4], di * a[5], di * a[6], di * a[7]);
}

// ---- KS-split aggregation: LDS acc over edge slice -> coalesced partial ----
__global__ void k_agg(const int* __restrict__ bbase, const unsigned* __restrict__ bedge,
                      const float* __restrict__ g_in, float* __restrict__ partial,
                      int KS) {
    __shared__ float acc[256 * 9];   // stride 9: bank-spread for atomics & reads
    int t = threadIdx.x;
    for (int q = t; q < 256 * 9; q += 256) acc[q] = 0.0f;
    __syncthreads();
    int b = blockIdx.x / KS, k = blockIdx.x % KS;
    int s = bbase[b], len = bbase[b + 1] - s;
    int lo = s + (int)((long long)len * k / KS);
    int hi = s + (int)((long long)len * (k + 1) / KS);
    const float4* g4 = (const float4*)g_in;
    for (int p = lo + t; p < hi; p += 256) {
        unsigned v = bedge[p];
        int r = (int)(v >> 8), lc = (int)(v & 255);
        float4 u = g4[(size_t)r * 2], w = g4[(size_t)r * 2 + 1];
        float* a = &acc[lc * 9];
        atomicAdd(a + 0, u.x); atomicAdd(a + 1, u.y);
        atomicAdd(a + 2, u.z); atomicAdd(a + 3, u.w);
        atomicAdd(a + 4, w.x); atomicAdd(a + 5, w.y);
        atomicAdd(a + 6, w.z); atomicAdd(a + 7, w.w);
    }
    __syncthreads();
    float4 v0 = make_float4(acc[t * 9 + 0], acc[t * 9 + 1], acc[t * 9 + 2], acc[t * 9 + 3]);
    float4 v1 = make_float4(acc[t * 9 + 4], acc[t * 9 + 5], acc[t * 9 + 6], acc[t * 9 + 7]);
    float4* pp = (float4*)(partial + ((size_t)blockIdx.x * 256 + t) * 8);
    pp[0] = v0; pp[1] = v1;
}

// ---- finish (mid layers): sum partials + self, relu, next projection ----
__global__ void k_finish(const float* __restrict__ partial, const float* __restrict__ g_in,
                         float* __restrict__ g_out, const float* __restrict__ dis,
                         const float* __restrict__ bias, const float* __restrict__ Wn,
                         int KS, int n) {
    __shared__ float Ws[HDIM * HDIM];
    __shared__ float bs[HDIM];
    int t = threadIdx.x;
    if (t < HDIM * HDIM) Ws[t] = Wn[t];
    if (t < HDIM) bs[t] = bias[t];
    __syncthreads();
    int i = blockIdx.x * blockDim.x + t;
    if (i >= n) return;
    const float4* g4 = (const float4*)g_in;
    float4 a0 = g4[(size_t)i * 2], a1 = g4[(size_t)i * 2 + 1];   // self term
    const float4* p4 = (const float4*)partial;
    size_t base = ((size_t)(i >> 8) * KS * 256 + (i & 255)) * 2;
    for (int k = 0; k < KS; ++k) {
        float4 u = p4[base + (size_t)k * 512], w = p4[base + (size_t)k * 512 + 1];
        a0.x += u.x; a0.y += u.y; a0.z += u.z; a0.w += u.w;
        a1.x += w.x; a1.y += w.y; a1.z += w.z; a1.w += w.w;
    }
    float di = dis[i];
    float h[HDIM];
    h[0] = fmaxf(di * a0.x + bs[0], 0.0f);
    h[1] = fmaxf(di * a0.y + bs[1], 0.0f);
    h[2] = fmaxf(di * a0.z + bs[2], 0.0f);
    h[3] = fmaxf(di * a0.w + bs[3], 0.0f);
    h[4] = fmaxf(di * a1.x + bs[4], 0.0f);
    h[5] = fmaxf(di * a1.y + bs[5], 0.0f);
    h[6] = fmaxf(di * a1.z + bs[6], 0.0f);
    h[7] = fmaxf(di * a1.w + bs[7], 0.0f);
    float gn[HDIM];
#pragma unroll
    for (int j = 0; j < HDIM; ++j) {
        float sj = 0.0f;
#pragma unroll
        for (int kk = 0; kk < HDIM; ++kk) sj += h[kk] * Ws[kk * HDIM + j];
        gn[j] = di * sj;
    }
    float4* gp = (float4*)(g_out + (size_t)i * HDIM);
    gp[0] = make_float4(gn[0], gn[1], gn[2], gn[3]);
    gp[1] = make_float4(gn[4], gn[5], gn[6], gn[7]);
}

// ---- finish (last layer): + proba head + mean reduce ----
__global__ void k_finish3(const float* __restrict__ partial, const float* __restrict__ g_in,
                          const float* __restrict__ dis, const float* __restrict__ b3,
                          const float* __restrict__ Wp, const float* __restrict__ bp,
                          float* __restrict__ out, float* __restrict__ mean_acc,
                          int KS, int n) {
    int t = threadIdx.x;
    int i = blockIdx.x * blockDim.x + t;
    float h[HDIM] = {0, 0, 0, 0, 0, 0, 0, 0};
    if (i < n) {
        const float4* g4 = (const float4*)g_in;
        float4 a0 = g4[(size_t)i * 2], a1 = g4[(size_t)i * 2 + 1];
        const float4* p4 = (const float4*)partial;
        size_t base = ((size_t)(i >> 8) * KS * 256 + (i & 255)) * 2;
        for (int k = 0; k < KS; ++k) {
            float4 u = p4[base + (size_t)k * 512], w = p4[base + (size_t)k * 512 + 1];
            a0.x += u.x; a0.y += u.y; a0.z += u.z; a0.w += u.w;
            a1.x += w.x; a1.y += w.y; a1.z += w.z; a1.w += w.w;
        }
        float di = dis[i];
        h[0] = fmaxf(di * a0.x + b3[0], 0.0f);
        h[1] = fmaxf(di * a0.y + b3[1], 0.0f);
        h[2] = fmaxf(di * a0.z + b3[2], 0.0f);
        h[3] = fmaxf(di * a0.w + b3[3], 0.0f);
        h[4] = fmaxf(di * a1.x + b3[4], 0.0f);
        h[5] = fmaxf(di * a1.y + b3[5], 0.0f);
        h[6] = fmaxf(di * a1.z + b3[6], 0.0f);
        h[7] = fmaxf(di * a1.w + b3[7], 0.0f);
        float p = bp[0];
#pragma unroll
        for (int j = 0; j < HDIM; ++j) p += h[j] * Wp[j];
        out[i] = p;
    }
#pragma unroll
    for (int j = 0; j < HDIM; ++j) {
        float sj = h[j];
#pragma unroll
        for (int o = 32; o > 0; o >>= 1) sj += __shfl_down(sj, o);
        if ((threadIdx.x & 63) == 0) atomicAdd(&mean_acc[j], sj);
    }
}

// ---- value head ----
__global__ void k_value(const float* __restrict__ mean_acc, const float* __restrict__ Wv,
                        const float* __restrict__ bv, float* __restrict__ out, int n) {
    if (threadIdx.x == 0 && blockIdx.x == 0) {
        float v = bv[0];
        float inv_n = 1.0f / (float)n;
#pragma unroll
        for (int j = 0; j < HDIM; ++j) v += (mean_acc[j] * inv_n) * Wv[j];
        out[n] = v;
    }
}

extern "C" void kernel_launch(void* const* d_in, const int* in_sizes, int n_in,
                              void* d_out, int out_size, void* d_ws, size_t ws_size,
                              hipStream_t stream) {
    const float* x  = (const float*)d_in[0];
    const int*   ei = (const int*)d_in[1];
    const float* W1 = (const float*)d_in[2];
    const float* b1 = (const float*)d_in[3];
    const float* W2 = (const float*)d_in[4];
    const float* b2 = (const float*)d_in[5];
    const float* W3 = (const float*)d_in[6];
    const float* b3 = (const float*)d_in[7];
    const float* Wp = (const float*)d_in[8];
    const float* bp = (const float*)d_in[9];
    const float* Wv = (const float*)d_in[10];
    const float* bv = (const float*)d_in[11];

    const int n = in_sizes[0] / 128;
    const int E = in_sizes[1] / 2;
    const int* row = ei;       // edge_index[0] = source
    const int* col = ei + E;   // edge_index[1] = target
    const int nbuck = (n + 255) >> 8;

    // workspace layout (4-byte units)
    int*      bhist = (int*)d_ws;                       // [0, 512)
    int*      bbase = bhist + 512;                      // [512, 1024)
    int*      bcur  = bhist + 1024;                     // [1024, 1536)
    float*    mean_acc = (float*)(bhist + 1536);        // [1536, 1544)
    int*      deg   = bhist + 2048;                     // n
    float*    dis   = (float*)(deg + n);                // n
    unsigned* bedge = (unsigned*)(dis + n);             // E
    float*    g_a   = (float*)(bedge + E);              // n*8 (16B aligned)
    float*    g_b   = g_a + (size_t)n * HDIM;           // n*8
    float*    partial = g_b + (size_t)n * HDIM;         // nbuck*KS*2048

    size_t base_ints = 2048 + 2 * (size_t)n + (size_t)E + 16 * (size_t)n;
    int KS = 8;
    while (KS > 1 && (base_ints + (size_t)nbuck * KS * 2048) * 4 > ws_size) KS >>= 1;

    dim3 blk(256);
    dim3 grid_n((n + 255) / 256);
    dim3 grid_n4(((size_t)n * 4 + 255) / 256);
    dim3 grid_e((E + 256 * EPB - 1) / (256 * EPB));
    dim3 grid_bk(nbuck * KS);

    k_zero  <<<grid_n, blk, 0, stream>>>(deg, bhist, mean_acc, n, nbuck);
    k_bhist <<<grid_e, blk, 0, stream>>>(col, E, nbuck, bhist);
    k_bscan <<<dim3(1), dim3(MAXBUCK), 0, stream>>>(bhist, nbuck, bbase, bcur);
    k_bucket<<<grid_e, blk, 0, stream>>>(row, col, E, nbuck, bcur, bedge);
    k_deg2  <<<grid_bk, blk, 0, stream>>>(bbase, bedge, deg, KS, n);
    k_proj1 <<<grid_n4, blk, 0, stream>>>(x, W1, deg, dis, g_a, n);

    // layer 1
    k_agg   <<<grid_bk, blk, 0, stream>>>(bbase, bedge, g_a, partial, KS);
    k_finish<<<grid_n, blk, 0, stream>>>(partial, g_a, g_b, dis, b1, W2, KS, n);
    // layer 2
    k_agg   <<<grid_bk, blk, 0, stream>>>(bbase, bedge, g_b, partial, KS);
    k_finish<<<grid_n, blk, 0, stream>>>(partial, g_b, g_a, dis, b2, W3, KS, n);
    // layer 3
    k_agg   <<<grid_bk, blk, 0, stream>>>(bbase, bedge, g_a, partial, KS);
    k_finish3<<<grid_n, blk, 0, stream>>>(partial, g_a, dis, b3, Wp, bp,
                                          (float*)d_out, mean_acc, KS, n);
    k_value <<<dim3(1), dim3(64), 0, stream>>>(mean_acc, Wv, bv, (float*)d_out, n);
}

// Round 5
// 606.438 us; speedup vs baseline: 13.4490x; 1.8836x over previous
//
#include <hip/hip_runtime.h>
#include <math.h>

// GCN forward, exact destination-sort + wave-segmented reduction.
// Pipeline: bucket histogram -> scan -> multisplit (bedge, grouped by 256-node
// bucket) -> per-bucket counting sort (sedge, sorted by dest; dest-local id in
// high byte) -> per layer: edge-parallel segmented wave reduce into acc[] with
// boundary-only global f32 atomics, then k_finish (relu + next 8x8 proj,
// re-zeroes acc).   g = dis * (h @ W);
// h_out[c] = relu( dis[c] * (sum_in g[row] + g[c]) + b )
// out[0..N-1] = proba, out[N] = value.

static constexpr int HDIM = 8;
#define EPB 16              // edges per thread in bucketing kernels
#define MAXBUCK 512
#define KS 8                // bucket slice split for k_aggseg

// ---- zero acc + bucket histogram + mean ----
__global__ void k_zero(int* __restrict__ bhist, float* __restrict__ mean_acc,
                       float* __restrict__ acc, int nbuck, int accn) {
    int i = blockIdx.x * 256 + threadIdx.x;
    if (i < accn) acc[i] = 0.0f;
    if (i < nbuck) bhist[i] = 0;
    if (i < HDIM) mean_acc[i] = 0.0f;
}

// ---- per-bucket histogram ----
__global__ void k_bhist(const int* __restrict__ col, int E, int nbuck,
                        int* __restrict__ bhist) {
    __shared__ int lcnt[MAXBUCK];
    for (int b = threadIdx.x; b < nbuck; b += 256) lcnt[b] = 0;
    __syncthreads();
    int base = blockIdx.x * (256 * EPB);
#pragma unroll
    for (int k = 0; k < EPB; ++k) {
        int e = base + k * 256 + threadIdx.x;
        if (e < E) atomicAdd(&lcnt[col[e] >> 8], 1);
    }
    __syncthreads();
    for (int b = threadIdx.x; b < nbuck; b += 256) {
        int c = lcnt[b];
        if (c) atomicAdd(&bhist[b], c);
    }
}

// ---- scan bucket counts -> bbase, init bcur ----
__global__ void k_bscan(const int* __restrict__ bhist, int nbuck,
                        int* __restrict__ bbase, int* __restrict__ bcur) {
    __shared__ int ts[MAXBUCK];
    int t = threadIdx.x;
    ts[t] = (t < nbuck) ? bhist[t] : 0;
    __syncthreads();
    for (int d = 1; d < MAXBUCK; d <<= 1) {
        int v = ts[t];
        int add = (t >= d) ? ts[t - d] : 0;
        __syncthreads();
        ts[t] = v + add;
        __syncthreads();
    }
    int ex = (t == 0) ? 0 : ts[t - 1];
    if (t < nbuck) { bbase[t] = ex; bcur[t] = ex; }
    if (t == nbuck) bbase[t] = ts[nbuck - 1];
}

// ---- multisplit scatter: bedge = (row<<8)|lc, grouped by bucket ----
__global__ void k_bucket(const int* __restrict__ row, const int* __restrict__ col,
                         int E, int nbuck, int* __restrict__ bcur,
                         unsigned* __restrict__ bedge) {
    __shared__ int lcnt[MAXBUCK];
    __shared__ int lbase[MAXBUCK];
    for (int b = threadIdx.x; b < nbuck; b += 256) lcnt[b] = 0;
    __syncthreads();
    int base = blockIdx.x * (256 * EPB);
    int myb[EPB], myrank[EPB];
    unsigned myv[EPB];
#pragma unroll
    for (int k = 0; k < EPB; ++k) {
        int e = base + k * 256 + threadIdx.x;
        if (e < E) {
            int c = col[e];
            int b = c >> 8;
            myb[k] = b;
            myrank[k] = atomicAdd(&lcnt[b], 1);
            myv[k] = ((unsigned)row[e] << 8) | (unsigned)(c & 255);
        } else myb[k] = -1;
    }
    __syncthreads();
    for (int b = threadIdx.x; b < nbuck; b += 256) {
        int c = lcnt[b];
        lbase[b] = c ? atomicAdd(&bcur[b], c) : 0;
    }
    __syncthreads();
#pragma unroll
    for (int k = 0; k < EPB; ++k)
        if (myb[k] >= 0) bedge[lbase[myb[k]] + myrank[k]] = myv[k];
}

// ---- per-bucket counting sort: sedge = (lc<<24)|row, sorted by lc; dis ----
__global__ void k_place(const int* __restrict__ bbase, const unsigned* __restrict__ bedge,
                        unsigned* __restrict__ sedge, float* __restrict__ dis, int n) {
    __shared__ int lcnt[256];
    __shared__ int lscan[256];
    __shared__ int lcur[256];
    int t = threadIdx.x, b = blockIdx.x;
    lcnt[t] = 0;
    __syncthreads();
    int s = bbase[b], e2 = bbase[b + 1];
    for (int p = s + t; p < e2; p += 256) atomicAdd(&lcnt[bedge[p] & 255], 1);
    __syncthreads();
    int c = lcnt[t];
    lscan[t] = c;
    __syncthreads();
    for (int d = 1; d < 256; d <<= 1) {
        int v = lscan[t];
        int add = (t >= d) ? lscan[t - d] : 0;
        __syncthreads();
        lscan[t] = v + add;
        __syncthreads();
    }
    lcur[t] = s + lscan[t] - c;          // exclusive scan -> cursor
    int i = (b << 8) + t;
    if (i < n) dis[i] = rsqrtf((float)(c + 1));   // +1 self loop
    __syncthreads();
    for (int p = s + t; p < e2; p += 256) {
        unsigned v = bedge[p];
        int lc = (int)(v & 255);
        int pos = atomicAdd(&lcur[lc], 1);
        sedge[pos] = ((unsigned)lc << 24) | (v >> 8);
    }
}

// ---- layer-1 projection, 4 threads/node: g = dis * (x @ W1) ----
__global__ void k_proj1(const float* __restrict__ x, const float* __restrict__ W1,
                        const float* __restrict__ dis, float* __restrict__ g, int n) {
    __shared__ float Ws[32 * 36];          // chunk-padded: [c][j][r], stride 36
    const float4* Ws4 = (const float4*)Ws;
    for (int t = threadIdx.x; t < 1024; t += 256) {
        int c = t >> 5, rem = t & 31, j = rem >> 2, r = rem & 3;
        Ws[c * 36 + j * 4 + r] = W1[(c * 4 + r) * 8 + j];
    }
    __syncthreads();
    int t4 = blockIdx.x * blockDim.x + threadIdx.x;
    int i = t4 >> 2, sub = t4 & 3;
    if (i >= n) return;
    const float4* x4 = (const float4*)x;
    float a[HDIM] = {0, 0, 0, 0, 0, 0, 0, 0};
#pragma unroll
    for (int iter = 0; iter < 8; ++iter) {
        int c = iter * 4 + sub;
        float4 xv = x4[(size_t)i * 32 + c];
#pragma unroll
        for (int j = 0; j < HDIM; ++j) {
            float4 wv = Ws4[c * 9 + j];
            a[j] += xv.x * wv.x + xv.y * wv.y + xv.z * wv.z + xv.w * wv.w;
        }
    }
#pragma unroll
    for (int j = 0; j < HDIM; ++j) {
        a[j] += __shfl_xor(a[j], 1);
        a[j] += __shfl_xor(a[j], 2);
    }
    float di = dis[i];
    float4* gp = (float4*)(g + (size_t)i * HDIM);
    if (sub == 0) gp[0] = make_float4(di * a[0], di * a[1], di * a[2], di * a[3]);
    if (sub == 1) gp[1] = make_float4(di * a[4], di * a[5], di * a[6], di * a[7]);
}

// ---- edge-parallel segmented wave reduction over sorted edges ----
__global__ void k_aggseg(const int* __restrict__ bbase, const unsigned* __restrict__ sedge,
                         const float* __restrict__ g, float* __restrict__ acc) {
    int b = blockIdx.x / KS, k = blockIdx.x % KS;
    int s = bbase[b], len = bbase[b + 1] - s;
    int lo = s + (int)((long long)len * k / KS);
    int hi = s + (int)((long long)len * (k + 1) / KS);
    int w = threadIdx.x >> 6, lane = threadIdx.x & 63;
    int wl = hi - lo;
    int wlo = lo + (int)((long long)wl * w / 4);
    int whi = lo + (int)((long long)wl * (w + 1) / 4);
    const float4* g4 = (const float4*)g;
    for (int ebase = wlo; ebase < whi; ebase += 64) {
        int e = ebase + lane;
        bool valid = e < whi;
        unsigned sv = valid ? sedge[e] : 0u;
        int key = valid ? (int)(sv >> 24) : 0x1FF;   // sentinel never matches
        float4 u = make_float4(0, 0, 0, 0), v = make_float4(0, 0, 0, 0);
        if (valid) {
            int r = (int)(sv & 0xFFFFFF);
            u = g4[(size_t)r * 2];
            v = g4[(size_t)r * 2 + 1];
        }
        // segmented inclusive scan by key (6 rounds)
#pragma unroll
        for (int d = 1; d < 64; d <<= 1) {
            int ku = __shfl_up(key, d);
            float ux = __shfl_up(u.x, d), uy = __shfl_up(u.y, d);
            float uz = __shfl_up(u.z, d), uw = __shfl_up(u.w, d);
            float vx = __shfl_up(v.x, d), vy = __shfl_up(v.y, d);
            float vz = __shfl_up(v.z, d), vw = __shfl_up(v.w, d);
            if (lane >= d && ku == key) {
                u.x += ux; u.y += uy; u.z += uz; u.w += uw;
                v.x += vx; v.y += vy; v.z += vz; v.w += vw;
            }
        }
        int kd = __shfl_down(key, 1);
        bool end = (lane == 63) || (kd != key);
        if (end && key < 256) {
            float* a = acc + (size_t)((b << 8) + key) * 8;
            atomicAdd(a + 0, u.x); atomicAdd(a + 1, u.y);
            atomicAdd(a + 2, u.z); atomicAdd(a + 3, u.w);
            atomicAdd(a + 4, v.x); atomicAdd(a + 5, v.y);
            atomicAdd(a + 6, v.z); atomicAdd(a + 7, v.w);
        }
    }
}

// ---- finish (mid layers): relu + next projection; g in place; re-zero acc ----
__global__ void k_finish(float* __restrict__ acc, float* __restrict__ g,
                         const float* __restrict__ dis, const float* __restrict__ bias,
                         const float* __restrict__ Wn, int n) {
    __shared__ float Ws[HDIM * HDIM];
    __shared__ float bs[HDIM];
    int t = threadIdx.x;
    if (t < HDIM * HDIM) Ws[t] = Wn[t];
    if (t < HDIM) bs[t] = bias[t];
    __syncthreads();
    int i = blockIdx.x * 256 + t;
    if (i >= n) return;
    float4* a4 = (float4*)(acc + (size_t)i * 8);
    float4* g4 = (float4*)(g + (size_t)i * 8);
    float4 a0 = a4[0], a1 = a4[1], s0 = g4[0], s1 = g4[1];
    a4[0] = make_float4(0, 0, 0, 0);           // re-zero for next layer
    a4[1] = make_float4(0, 0, 0, 0);
    float di = dis[i];
    float h[HDIM];
    h[0] = fmaxf(di * (a0.x + s0.x) + bs[0], 0.0f);
    h[1] = fmaxf(di * (a0.y + s0.y) + bs[1], 0.0f);
    h[2] = fmaxf(di * (a0.z + s0.z) + bs[2], 0.0f);
    h[3] = fmaxf(di * (a0.w + s0.w) + bs[3], 0.0f);
    h[4] = fmaxf(di * (a1.x + s1.x) + bs[4], 0.0f);
    h[5] = fmaxf(di * (a1.y + s1.y) + bs[5], 0.0f);
    h[6] = fmaxf(di * (a1.z + s1.z) + bs[6], 0.0f);
    h[7] = fmaxf(di * (a1.w + s1.w) + bs[7], 0.0f);
    float gn[HDIM];
#pragma unroll
    for (int j = 0; j < HDIM; ++j) {
        float sj = 0.0f;
#pragma unroll
        for (int kk = 0; kk < HDIM; ++kk) sj += h[kk] * Ws[kk * HDIM + j];
        gn[j] = di * sj;
    }
    g4[0] = make_float4(gn[0], gn[1], gn[2], gn[3]);
    g4[1] = make_float4(gn[4], gn[5], gn[6], gn[7]);
}

// ---- finish (last layer): + proba head + mean reduce ----
__global__ void k_finish3(const float* __restrict__ acc, const float* __restrict__ g,
                          const float* __restrict__ dis, const float* __restrict__ b3,
                          const float* __restrict__ Wp, const float* __restrict__ bp,
                          float* __restrict__ out, float* __restrict__ mean_acc, int n) {
    int t = threadIdx.x;
    int i = blockIdx.x * 256 + t;
    float h[HDIM] = {0, 0, 0, 0, 0, 0, 0, 0};
    if (i < n) {
        const float4* a4 = (const float4*)(acc + (size_t)i * 8);
        const float4* g4 = (const float4*)(g + (size_t)i * 8);
        float4 a0 = a4[0], a1 = a4[1], s0 = g4[0], s1 = g4[1];
        float di = dis[i];
        h[0] = fmaxf(di * (a0.x + s0.x) + b3[0], 0.0f);
        h[1] = fmaxf(di * (a0.y + s0.y) + b3[1], 0.0f);
        h[2] = fmaxf(di * (a0.z + s0.z) + b3[2], 0.0f);
        h[3] = fmaxf(di * (a0.w + s0.w) + b3[3], 0.0f);
        h[4] = fmaxf(di * (a1.x + s1.x) + b3[4], 0.0f);
        h[5] = fmaxf(di * (a1.y + s1.y) + b3[5], 0.0f);
        h[6] = fmaxf(di * (a1.z + s1.z) + b3[6], 0.0f);
        h[7] = fmaxf(di * (a1.w + s1.w) + b3[7], 0.0f);
        float p = bp[0];
#pragma unroll
        for (int j = 0; j < HDIM; ++j) p += h[j] * Wp[j];
        out[i] = p;
    }
#pragma unroll
    for (int j = 0; j < HDIM; ++j) {
        float sj = h[j];
#pragma unroll
        for (int o = 32; o > 0; o >>= 1) sj += __shfl_down(sj, o);
        if ((threadIdx.x & 63) == 0) atomicAdd(&mean_acc[j], sj);
    }
}

// ---- value head ----
__global__ void k_value(const float* __restrict__ mean_acc, const float* __restrict__ Wv,
                        const float* __restrict__ bv, float* __restrict__ out, int n) {
    if (threadIdx.x == 0 && blockIdx.x == 0) {
        float v = bv[0];
        float inv_n = 1.0f / (float)n;
#pragma unroll
        for (int j = 0; j < HDIM; ++j) v += (mean_acc[j] * inv_n) * Wv[j];
        out[n] = v;
    }
}

extern "C" void kernel_launch(void* const* d_in, const int* in_sizes, int n_in,
                              void* d_out, int out_size, void* d_ws, size_t ws_size,
                              hipStream_t stream) {
    const float* x  = (const float*)d_in[0];
    const int*   ei = (const int*)d_in[1];
    const float* W1 = (const float*)d_in[2];
    const float* b1 = (const float*)d_in[3];
    const float* W2 = (const float*)d_in[4];
    const float* b2 = (const float*)d_in[5];
    const float* W3 = (const float*)d_in[6];
    const float* b3 = (const float*)d_in[7];
    const float* Wp = (const float*)d_in[8];
    const float* bp = (const float*)d_in[9];
    const float* Wv = (const float*)d_in[10];
    const float* bv = (const float*)d_in[11];

    const int n = in_sizes[0] / 128;
    const int E = in_sizes[1] / 2;
    const int* row = ei;       // edge_index[0] = source
    const int* col = ei + E;   // edge_index[1] = target
    const int nbuck = (n + 255) >> 8;

    // workspace layout (4-byte units); ~58 MB total
    int*      bhist = (int*)d_ws;                   // 512
    int*      bbase = bhist + 512;                  // 512
    int*      bcur  = bhist + 1024;                 // 512
    float*    mean_acc = (float*)(bhist + 1536);    // 8 (pad to 2048)
    float*    dis   = (float*)(bhist + 2048);       // n
    unsigned* bedge = (unsigned*)(dis + n);         // E
    unsigned* sedge = bedge + E;                    // E
    float*    g     = (float*)(sedge + E);          // n*8 (16B aligned)
    float*    acc   = g + (size_t)n * HDIM;         // n*8

    const int accn = n * HDIM;
    dim3 blk(256);
    dim3 grid_z((accn + 255) / 256);
    dim3 grid_n((n + 255) / 256);
    dim3 grid_n4(((size_t)n * 4 + 255) / 256);
    dim3 grid_e((E + 256 * EPB - 1) / (256 * EPB));
    dim3 grid_b(nbuck);
    dim3 grid_bk(nbuck * KS);

    k_zero  <<<grid_z, blk, 0, stream>>>(bhist, mean_acc, acc, nbuck, accn);
    k_bhist <<<grid_e, blk, 0, stream>>>(col, E, nbuck, bhist);
    k_bscan <<<dim3(1), dim3(MAXBUCK), 0, stream>>>(bhist, nbuck, bbase, bcur);
    k_bucket<<<grid_e, blk, 0, stream>>>(row, col, E, nbuck, bcur, bedge);
    k_place <<<grid_b, blk, 0, stream>>>(bbase, bedge, sedge, dis, n);
    k_proj1 <<<grid_n4, blk, 0, stream>>>(x, W1, dis, g, n);

    // layer 1
    k_aggseg<<<grid_bk, blk, 0, stream>>>(bbase, sedge, g, acc);
    k_finish<<<grid_n, blk, 0, stream>>>(acc, g, dis, b1, W2, n);
    // layer 2
    k_aggseg<<<grid_bk, blk, 0, stream>>>(bbase, sedge, g, acc);
    k_finish<<<grid_n, blk, 0, stream>>>(acc, g, dis, b2, W3, n);
    // layer 3
    k_aggseg<<<grid_bk, blk, 0, stream>>>(bbase, sedge, g, acc);
    k_finish3<<<grid_n, blk, 0, stream>>>(acc, g, dis, b3, Wp, bp,
                                          (float*)d_out, mean_acc, n);
    k_value <<<dim3(1), dim3(64), 0, stream>>>(mean_acc, Wv, bv, (float*)d_out, n);
}

// Round 6
// 451.246 us; speedup vs baseline: 18.0743x; 1.3439x over previous
//
#include <hip/hip_runtime.h>
#include <math.h>

// GCN forward, exact destination-sort + wave-segmented reduction.
// Pipeline: bucket histogram -> scan -> multisplit (bedge, grouped by 256-node
// bucket) -> per-bucket counting sort (sedge, sorted by dest; dest-local id in
// high byte) -> per layer: edge-parallel segmented wave reduce into acc[] with
// boundary-only global f32 atomics, then k_finish (relu + next 8x8 proj,
// re-zeroes acc).  Mean pool via per-block partials + tiny second-stage
// reduction (no contended global atomics).
// g = dis * (h @ W);  h_out[c] = relu( dis[c] * (sum_in g[row] + g[c]) + b )
// out[0..N-1] = proba, out[N] = value.

static constexpr int HDIM = 8;
#define EPB 16              // edges per thread in bucketing kernels
#define MAXBUCK 512
#define KS 8                // bucket slice split for k_aggseg

// ---- zero acc + bucket histogram ----
__global__ void k_zero(int* __restrict__ bhist, float* __restrict__ acc,
                       int nbuck, int accn) {
    int i = blockIdx.x * 256 + threadIdx.x;
    if (i < accn) acc[i] = 0.0f;
    if (i < nbuck) bhist[i] = 0;
}

// ---- per-bucket histogram ----
__global__ void k_bhist(const int* __restrict__ col, int E, int nbuck,
                        int* __restrict__ bhist) {
    __shared__ int lcnt[MAXBUCK];
    for (int b = threadIdx.x; b < nbuck; b += 256) lcnt[b] = 0;
    __syncthreads();
    int base = blockIdx.x * (256 * EPB);
#pragma unroll
    for (int k = 0; k < EPB; ++k) {
        int e = base + k * 256 + threadIdx.x;
        if (e < E) atomicAdd(&lcnt[col[e] >> 8], 1);
    }
    __syncthreads();
    for (int b = threadIdx.x; b < nbuck; b += 256) {
        int c = lcnt[b];
        if (c) atomicAdd(&bhist[b], c);
    }
}

// ---- scan bucket counts -> bbase, init bcur ----
__global__ void k_bscan(const int* __restrict__ bhist, int nbuck,
                        int* __restrict__ bbase, int* __restrict__ bcur) {
    __shared__ int ts[MAXBUCK];
    int t = threadIdx.x;
    ts[t] = (t < nbuck) ? bhist[t] : 0;
    __syncthreads();
    for (int d = 1; d < MAXBUCK; d <<= 1) {
        int v = ts[t];
        int add = (t >= d) ? ts[t - d] : 0;
        __syncthreads();
        ts[t] = v + add;
        __syncthreads();
    }
    int ex = (t == 0) ? 0 : ts[t - 1];
    if (t < nbuck) { bbase[t] = ex; bcur[t] = ex; }
    if (t == nbuck) bbase[t] = ts[nbuck - 1];
}

// ---- multisplit scatter: bedge = (row<<8)|lc, grouped by bucket ----
__global__ void k_bucket(const int* __restrict__ row, const int* __restrict__ col,
                         int E, int nbuck, int* __restrict__ bcur,
                         unsigned* __restrict__ bedge) {
    __shared__ int lcnt[MAXBUCK];
    __shared__ int lbase[MAXBUCK];
    for (int b = threadIdx.x; b < nbuck; b += 256) lcnt[b] = 0;
    __syncthreads();
    int base = blockIdx.x * (256 * EPB);
    int myb[EPB], myrank[EPB];
    unsigned myv[EPB];
#pragma unroll
    for (int k = 0; k < EPB; ++k) {
        int e = base + k * 256 + threadIdx.x;
        if (e < E) {
            int c = col[e];
            int b = c >> 8;
            myb[k] = b;
            myrank[k] = atomicAdd(&lcnt[b], 1);
            myv[k] = ((unsigned)row[e] << 8) | (unsigned)(c & 255);
        } else myb[k] = -1;
    }
    __syncthreads();
    for (int b = threadIdx.x; b < nbuck; b += 256) {
        int c = lcnt[b];
        lbase[b] = c ? atomicAdd(&bcur[b], c) : 0;
    }
    __syncthreads();
#pragma unroll
    for (int k = 0; k < EPB; ++k)
        if (myb[k] >= 0) bedge[lbase[myb[k]] + myrank[k]] = myv[k];
}

// ---- per-bucket counting sort: sedge = (lc<<24)|row, sorted by lc; dis ----
__global__ void k_place(const int* __restrict__ bbase, const unsigned* __restrict__ bedge,
                        unsigned* __restrict__ sedge, float* __restrict__ dis, int n) {
    __shared__ int lcnt[256];
    __shared__ int lscan[256];
    __shared__ int lcur[256];
    int t = threadIdx.x, b = blockIdx.x;
    lcnt[t] = 0;
    __syncthreads();
    int s = bbase[b], e2 = bbase[b + 1];
    for (int p = s + t; p < e2; p += 256) atomicAdd(&lcnt[bedge[p] & 255], 1);
    __syncthreads();
    int c = lcnt[t];
    lscan[t] = c;
    __syncthreads();
    for (int d = 1; d < 256; d <<= 1) {
        int v = lscan[t];
        int add = (t >= d) ? lscan[t - d] : 0;
        __syncthreads();
        lscan[t] = v + add;
        __syncthreads();
    }
    lcur[t] = s + lscan[t] - c;          // exclusive scan -> cursor
    int i = (b << 8) + t;
    if (i < n) dis[i] = rsqrtf((float)(c + 1));   // +1 self loop
    __syncthreads();
    for (int p = s + t; p < e2; p += 256) {
        unsigned v = bedge[p];
        int lc = (int)(v & 255);
        int pos = atomicAdd(&lcur[lc], 1);
        sedge[pos] = ((unsigned)lc << 24) | (v >> 8);
    }
}

// ---- layer-1 projection, 4 threads/node: g = dis * (x @ W1) ----
__global__ void k_proj1(const float* __restrict__ x, const float* __restrict__ W1,
                        const float* __restrict__ dis, float* __restrict__ g, int n) {
    __shared__ float Ws[32 * 36];          // chunk-padded: [c][j][r], stride 36
    const float4* Ws4 = (const float4*)Ws;
    for (int t = threadIdx.x; t < 1024; t += 256) {
        int c = t >> 5, rem = t & 31, j = rem >> 2, r = rem & 3;
        Ws[c * 36 + j * 4 + r] = W1[(c * 4 + r) * 8 + j];
    }
    __syncthreads();
    int t4 = blockIdx.x * blockDim.x + threadIdx.x;
    int i = t4 >> 2, sub = t4 & 3;
    if (i >= n) return;
    const float4* x4 = (const float4*)x;
    float a[HDIM] = {0, 0, 0, 0, 0, 0, 0, 0};
#pragma unroll
    for (int iter = 0; iter < 8; ++iter) {
        int c = iter * 4 + sub;
        float4 xv = x4[(size_t)i * 32 + c];
#pragma unroll
        for (int j = 0; j < HDIM; ++j) {
            float4 wv = Ws4[c * 9 + j];
            a[j] += xv.x * wv.x + xv.y * wv.y + xv.z * wv.z + xv.w * wv.w;
        }
    }
#pragma unroll
    for (int j = 0; j < HDIM; ++j) {
        a[j] += __shfl_xor(a[j], 1);
        a[j] += __shfl_xor(a[j], 2);
    }
    float di = dis[i];
    float4* gp = (float4*)(g + (size_t)i * HDIM);
    if (sub == 0) gp[0] = make_float4(di * a[0], di * a[1], di * a[2], di * a[3]);
    if (sub == 1) gp[1] = make_float4(di * a[4], di * a[5], di * a[6], di * a[7]);
}

// ---- edge-parallel segmented wave reduction over sorted edges ----
__global__ void k_aggseg(const int* __restrict__ bbase, const unsigned* __restrict__ sedge,
                         const float* __restrict__ g, float* __restrict__ acc) {
    int b = blockIdx.x / KS, k = blockIdx.x % KS;
    int s = bbase[b], len = bbase[b + 1] - s;
    int lo = s + (int)((long long)len * k / KS);
    int hi = s + (int)((long long)len * (k + 1) / KS);
    int w = threadIdx.x >> 6, lane = threadIdx.x & 63;
    int wl = hi - lo;
    int wlo = lo + (int)((long long)wl * w / 4);
    int whi = lo + (int)((long long)wl * (w + 1) / 4);
    const float4* g4 = (const float4*)g;
    for (int ebase = wlo; ebase < whi; ebase += 64) {
        int e = ebase + lane;
        bool valid = e < whi;
        unsigned sv = valid ? sedge[e] : 0u;
        int key = valid ? (int)(sv >> 24) : 0x1FF;   // sentinel never matches
        float4 u = make_float4(0, 0, 0, 0), v = make_float4(0, 0, 0, 0);
        if (valid) {
            int r = (int)(sv & 0xFFFFFF);
            u = g4[(size_t)r * 2];
            v = g4[(size_t)r * 2 + 1];
        }
        // segmented inclusive scan by key (6 rounds)
#pragma unroll
        for (int d = 1; d < 64; d <<= 1) {
            int ku = __shfl_up(key, d);
            float ux = __shfl_up(u.x, d), uy = __shfl_up(u.y, d);
            float uz = __shfl_up(u.z, d), uw = __shfl_up(u.w, d);
            float vx = __shfl_up(v.x, d), vy = __shfl_up(v.y, d);
            float vz = __shfl_up(v.z, d), vw = __shfl_up(v.w, d);
            if (lane >= d && ku == key) {
                u.x += ux; u.y += uy; u.z += uz; u.w += uw;
                v.x += vx; v.y += vy; v.z += vz; v.w += vw;
            }
        }
        int kd = __shfl_down(key, 1);
        bool end = (lane == 63) || (kd != key);
        if (end && key < 256) {
            float* a = acc + (size_t)((b << 8) + key) * 8;
            atomicAdd(a + 0, u.x); atomicAdd(a + 1, u.y);
            atomicAdd(a + 2, u.z); atomicAdd(a + 3, u.w);
            atomicAdd(a + 4, v.x); atomicAdd(a + 5, v.y);
            atomicAdd(a + 6, v.z); atomicAdd(a + 7, v.w);
        }
    }
}

// ---- finish (mid layers): relu + next projection; g in place; re-zero acc ----
__global__ void k_finish(float* __restrict__ acc, float* __restrict__ g,
                         const float* __restrict__ dis, const float* __restrict__ bias,
                         const float* __restrict__ Wn, int n) {
    __shared__ float Ws[HDIM * HDIM];
    __shared__ float bs[HDIM];
    int t = threadIdx.x;
    if (t < HDIM * HDIM) Ws[t] = Wn[t];
    if (t < HDIM) bs[t] = bias[t];
    __syncthreads();
    int i = blockIdx.x * 256 + t;
    if (i >= n) return;
    float4* a4 = (float4*)(acc + (size_t)i * 8);
    float4* g4 = (float4*)(g + (size_t)i * 8);
    float4 a0 = a4[0], a1 = a4[1], s0 = g4[0], s1 = g4[1];
    a4[0] = make_float4(0, 0, 0, 0);           // re-zero for next layer
    a4[1] = make_float4(0, 0, 0, 0);
    float di = dis[i];
    float h[HDIM];
    h[0] = fmaxf(di * (a0.x + s0.x) + bs[0], 0.0f);
    h[1] = fmaxf(di * (a0.y + s0.y) + bs[1], 0.0f);
    h[2] = fmaxf(di * (a0.z + s0.z) + bs[2], 0.0f);
    h[3] = fmaxf(di * (a0.w + s0.w) + bs[3], 0.0f);
    h[4] = fmaxf(di * (a1.x + s1.x) + bs[4], 0.0f);
    h[5] = fmaxf(di * (a1.y + s1.y) + bs[5], 0.0f);
    h[6] = fmaxf(di * (a1.z + s1.z) + bs[6], 0.0f);
    h[7] = fmaxf(di * (a1.w + s1.w) + bs[7], 0.0f);
    float gn[HDIM];
#pragma unroll
    for (int j = 0; j < HDIM; ++j) {
        float sj = 0.0f;
#pragma unroll
        for (int kk = 0; kk < HDIM; ++kk) sj += h[kk] * Ws[kk * HDIM + j];
        gn[j] = di * sj;
    }
    g4[0] = make_float4(gn[0], gn[1], gn[2], gn[3]);
    g4[1] = make_float4(gn[4], gn[5], gn[6], gn[7]);
}

// ---- finish (last layer): + proba head; per-block mean partial (no atomics) ----
__global__ void k_finish3(const float* __restrict__ acc, const float* __restrict__ g,
                          const float* __restrict__ dis, const float* __restrict__ b3,
                          const float* __restrict__ Wp, const float* __restrict__ bp,
                          float* __restrict__ out, float* __restrict__ partial, int n) {
    __shared__ float red[4][HDIM];
    int t = threadIdx.x;
    int i = blockIdx.x * 256 + t;
    float h[HDIM] = {0, 0, 0, 0, 0, 0, 0, 0};
    if (i < n) {
        const float4* a4 = (const float4*)(acc + (size_t)i * 8);
        const float4* g4 = (const float4*)(g + (size_t)i * 8);
        float4 a0 = a4[0], a1 = a4[1], s0 = g4[0], s1 = g4[1];
        float di = dis[i];
        h[0] = fmaxf(di * (a0.x + s0.x) + b3[0], 0.0f);
        h[1] = fmaxf(di * (a0.y + s0.y) + b3[1], 0.0f);
        h[2] = fmaxf(di * (a0.z + s0.z) + b3[2], 0.0f);
        h[3] = fmaxf(di * (a0.w + s0.w) + b3[3], 0.0f);
        h[4] = fmaxf(di * (a1.x + s1.x) + b3[4], 0.0f);
        h[5] = fmaxf(di * (a1.y + s1.y) + b3[5], 0.0f);
        h[6] = fmaxf(di * (a1.z + s1.z) + b3[6], 0.0f);
        h[7] = fmaxf(di * (a1.w + s1.w) + b3[7], 0.0f);
        float p = bp[0];
#pragma unroll
        for (int j = 0; j < HDIM; ++j) p += h[j] * Wp[j];
        out[i] = p;
    }
    int w = t >> 6, lane = t & 63;
#pragma unroll
    for (int j = 0; j < HDIM; ++j) {
        float sj = h[j];
#pragma unroll
        for (int o = 32; o > 0; o >>= 1) sj += __shfl_down(sj, o);
        if (lane == 0) red[w][j] = sj;
    }
    __syncthreads();
    if (t < HDIM)
        partial[(size_t)blockIdx.x * HDIM + t] =
            red[0][t] + red[1][t] + red[2][t] + red[3][t];
}

// ---- value head: reduce per-block partials ----
__global__ void k_value(const float* __restrict__ partial, int nblocks,
                        const float* __restrict__ Wv, const float* __restrict__ bv,
                        float* __restrict__ out, int n) {
    __shared__ float red[256];
    int t = threadIdx.x;
    int j = t & 7, c = t >> 3;               // 32 chunks x 8 components
    float v = 0.0f;
    for (int b = c; b < nblocks; b += 32) v += partial[(size_t)b * HDIM + j];
    red[t] = v;
    __syncthreads();
    for (int d = 128; d >= 8; d >>= 1) {
        if (t < d) red[t] += red[t + d];
        __syncthreads();
    }
    if (t == 0) {
        float val = bv[0];
        float inv_n = 1.0f / (float)n;
#pragma unroll
        for (int jj = 0; jj < HDIM; ++jj) val += (red[jj] * inv_n) * Wv[jj];
        out[n] = val;
    }
}

extern "C" void kernel_launch(void* const* d_in, const int* in_sizes, int n_in,
                              void* d_out, int out_size, void* d_ws, size_t ws_size,
                              hipStream_t stream) {
    const float* x  = (const float*)d_in[0];
    const int*   ei = (const int*)d_in[1];
    const float* W1 = (const float*)d_in[2];
    const float* b1 = (const float*)d_in[3];
    const float* W2 = (const float*)d_in[4];
    const float* b2 = (const float*)d_in[5];
    const float* W3 = (const float*)d_in[6];
    const float* b3 = (const float*)d_in[7];
    const float* Wp = (const float*)d_in[8];
    const float* bp = (const float*)d_in[9];
    const float* Wv = (const float*)d_in[10];
    const float* bv = (const float*)d_in[11];

    const int n = in_sizes[0] / 128;
    const int E = in_sizes[1] / 2;
    const int* row = ei;       // edge_index[0] = source
    const int* col = ei + E;   // edge_index[1] = target
    const int nbuck = (n + 255) >> 8;

    // workspace layout (4-byte units); ~58 MB total
    int*      bhist = (int*)d_ws;                   // 512
    int*      bbase = bhist + 512;                  // 512
    int*      bcur  = bhist + 1024;                 // 512
    float*    partial = (float*)(bhist + 1536);     // nbuck*8 (<= 4096)
    float*    dis   = (float*)(bhist + 6144);       // n
    unsigned* bedge = (unsigned*)(dis + n);         // E
    unsigned* sedge = bedge + E;                    // E
    float*    g     = (float*)(sedge + E);          // n*8 (16B aligned)
    float*    acc   = g + (size_t)n * HDIM;         // n*8

    const int accn = n * HDIM;
    dim3 blk(256);
    dim3 grid_z((accn + 255) / 256);
    dim3 grid_n((n + 255) / 256);
    dim3 grid_n4(((size_t)n * 4 + 255) / 256);
    dim3 grid_e((E + 256 * EPB - 1) / (256 * EPB));
    dim3 grid_b(nbuck);
    dim3 grid_bk(nbuck * KS);
    const int nblocks = (n + 255) / 256;

    k_zero  <<<grid_z, blk, 0, stream>>>(bhist, acc, nbuck, accn);
    k_bhist <<<grid_e, blk, 0, stream>>>(col, E, nbuck, bhist);
    k_bscan <<<dim3(1), dim3(MAXBUCK), 0, stream>>>(bhist, nbuck, bbase, bcur);
    k_bucket<<<grid_e, blk, 0, stream>>>(row, col, E, nbuck, bcur, bedge);
    k_place <<<grid_b, blk, 0, stream>>>(bbase, bedge, sedge, dis, n);
    k_proj1 <<<grid_n4, blk, 0, stream>>>(x, W1, dis, g, n);

    // layer 1
    k_aggseg<<<grid_bk, blk, 0, stream>>>(bbase, sedge, g, acc);
    k_finish<<<grid_n, blk, 0, stream>>>(acc, g, dis, b1, W2, n);
    // layer 2
    k_aggseg<<<grid_bk, blk, 0, stream>>>(bbase, sedge, g, acc);
    k_finish<<<grid_n, blk, 0, stream>>>(acc, g, dis, b2, W3, n);
    // layer 3
    k_aggseg<<<grid_bk, blk, 0, stream>>>(bbase, sedge, g, acc);
    k_finish3<<<grid_n, blk, 0, stream>>>(acc, g, dis, b3, Wp, bp,
                                          (float*)d_out, partial, n);
    k_value <<<dim3(1), blk, 0, stream>>>(partial, nblocks, Wv, bv,
                                          (float*)d_out, n);
}

// Round 7
// 376.736 us; speedup vs baseline: 21.6490x; 1.1978x over previous
//
#include <hip/hip_runtime.h>
#include <math.h>

// GCN forward, exact per-node CSR (bucket multisplit + counting sort) +
// fully-fused CSR-gather layers (4 lanes per node, zero f32 atomics).
// Pipeline: bhist -> bscan -> bucket multisplit (bedge) -> k_place (perm
// sorted by dest, noff CSR offsets, dis) -> k_proj1 -> 3x k_flayer (gather +
// quad butterfly + relu + next 8x8 proj), last one also emits proba and
// per-block mean partials -> k_value.
// g = dis * (h @ W);  h_out[c] = relu( dis[c] * (sum_in g[row] + g[c]) + b )
// out[0..N-1] = proba, out[N] = value.

static constexpr int HDIM = 8;
#define EPB 16              // edges per thread in bucketing kernels
#define MAXBUCK 512

// ---- zero bucket histogram ----
__global__ void k_zero(int* __restrict__ bhist, int nbuck) {
    int i = blockIdx.x * 256 + threadIdx.x;
    if (i < nbuck) bhist[i] = 0;
}

// ---- per-bucket histogram ----
__global__ void k_bhist(const int* __restrict__ col, int E, int nbuck,
                        int* __restrict__ bhist) {
    __shared__ int lcnt[MAXBUCK];
    for (int b = threadIdx.x; b < nbuck; b += 256) lcnt[b] = 0;
    __syncthreads();
    int base = blockIdx.x * (256 * EPB);
#pragma unroll
    for (int k = 0; k < EPB; ++k) {
        int e = base + k * 256 + threadIdx.x;
        if (e < E) atomicAdd(&lcnt[col[e] >> 8], 1);
    }
    __syncthreads();
    for (int b = threadIdx.x; b < nbuck; b += 256) {
        int c = lcnt[b];
        if (c) atomicAdd(&bhist[b], c);
    }
}

// ---- scan bucket counts -> bbase, init bcur ----
__global__ void k_bscan(const int* __restrict__ bhist, int nbuck,
                        int* __restrict__ bbase, int* __restrict__ bcur) {
    __shared__ int ts[MAXBUCK];
    int t = threadIdx.x;
    ts[t] = (t < nbuck) ? bhist[t] : 0;
    __syncthreads();
    for (int d = 1; d < MAXBUCK; d <<= 1) {
        int v = ts[t];
        int add = (t >= d) ? ts[t - d] : 0;
        __syncthreads();
        ts[t] = v + add;
        __syncthreads();
    }
    int ex = (t == 0) ? 0 : ts[t - 1];
    if (t < nbuck) { bbase[t] = ex; bcur[t] = ex; }
    if (t == nbuck) bbase[t] = ts[nbuck - 1];
}

// ---- multisplit scatter: bedge = (row<<8)|lc, grouped by bucket ----
__global__ void k_bucket(const int* __restrict__ row, const int* __restrict__ col,
                         int E, int nbuck, int* __restrict__ bcur,
                         unsigned* __restrict__ bedge) {
    __shared__ int lcnt[MAXBUCK];
    __shared__ int lbase[MAXBUCK];
    for (int b = threadIdx.x; b < nbuck; b += 256) lcnt[b] = 0;
    __syncthreads();
    int base = blockIdx.x * (256 * EPB);
    int myb[EPB], myrank[EPB];
    unsigned myv[EPB];
#pragma unroll
    for (int k = 0; k < EPB; ++k) {
        int e = base + k * 256 + threadIdx.x;
        if (e < E) {
            int c = col[e];
            int b = c >> 8;
            myb[k] = b;
            myrank[k] = atomicAdd(&lcnt[b], 1);
            myv[k] = ((unsigned)row[e] << 8) | (unsigned)(c & 255);
        } else myb[k] = -1;
    }
    __syncthreads();
    for (int b = threadIdx.x; b < nbuck; b += 256) {
        int c = lcnt[b];
        lbase[b] = c ? atomicAdd(&bcur[b], c) : 0;
    }
    __syncthreads();
#pragma unroll
    for (int k = 0; k < EPB; ++k)
        if (myb[k] >= 0) bedge[lbase[myb[k]] + myrank[k]] = myv[k];
}

// ---- per-bucket counting sort -> perm (row ids, dest-sorted), noff CSR, dis ----
__global__ void k_place(const int* __restrict__ bbase, const unsigned* __restrict__ bedge,
                        int* __restrict__ perm, int* __restrict__ noff,
                        float* __restrict__ dis, int n, int E) {
    __shared__ int lcnt[256];
    __shared__ int lscan[256];
    __shared__ int lcur[256];
    int t = threadIdx.x, b = blockIdx.x;
    lcnt[t] = 0;
    __syncthreads();
    int s = bbase[b], e2 = bbase[b + 1];
    for (int p = s + t; p < e2; p += 256) atomicAdd(&lcnt[bedge[p] & 255], 1);
    __syncthreads();
    int c = lcnt[t];
    lscan[t] = c;
    __syncthreads();
    for (int d = 1; d < 256; d <<= 1) {
        int v = lscan[t];
        int add = (t >= d) ? lscan[t - d] : 0;
        __syncthreads();
        lscan[t] = v + add;
        __syncthreads();
    }
    int start = s + lscan[t] - c;        // exclusive scan -> node edge start
    lcur[t] = start;
    int i = (b << 8) + t;
    if (i < n) {
        noff[i] = start;
        dis[i] = rsqrtf((float)(c + 1));   // +1 self loop
    }
    if (i == n) noff[n] = E;
    __syncthreads();
    for (int p = s + t; p < e2; p += 256) {
        unsigned v = bedge[p];
        int lc = (int)(v & 255);
        int pos = atomicAdd(&lcur[lc], 1);
        perm[pos] = (int)(v >> 8);
    }
}

// ---- layer-1 projection, 4 threads/node: g = dis * (x @ W1) ----
__global__ void k_proj1(const float* __restrict__ x, const float* __restrict__ W1,
                        const float* __restrict__ dis, float* __restrict__ g, int n) {
    __shared__ float Ws[32 * 36];          // chunk-padded: [c][j][r], stride 36
    const float4* Ws4 = (const float4*)Ws;
    for (int t = threadIdx.x; t < 1024; t += 256) {
        int c = t >> 5, rem = t & 31, j = rem >> 2, r = rem & 3;
        Ws[c * 36 + j * 4 + r] = W1[(c * 4 + r) * 8 + j];
    }
    __syncthreads();
    int t4 = blockIdx.x * blockDim.x + threadIdx.x;
    int i = t4 >> 2, sub = t4 & 3;
    if (i >= n) return;
    const float4* x4 = (const float4*)x;
    float a[HDIM] = {0, 0, 0, 0, 0, 0, 0, 0};
#pragma unroll
    for (int iter = 0; iter < 8; ++iter) {
        int c = iter * 4 + sub;
        float4 xv = x4[(size_t)i * 32 + c];
#pragma unroll
        for (int j = 0; j < HDIM; ++j) {
            float4 wv = Ws4[c * 9 + j];
            a[j] += xv.x * wv.x + xv.y * wv.y + xv.z * wv.z + xv.w * wv.w;
        }
    }
#pragma unroll
    for (int j = 0; j < HDIM; ++j) {
        a[j] += __shfl_xor(a[j], 1);
        a[j] += __shfl_xor(a[j], 2);
    }
    float di = dis[i];
    float4* gp = (float4*)(g + (size_t)i * HDIM);
    if (sub == 0) gp[0] = make_float4(di * a[0], di * a[1], di * a[2], di * a[3]);
    if (sub == 1) gp[1] = make_float4(di * a[4], di * a[5], di * a[6], di * a[7]);
}

// ---- fused mid layer: CSR gather (4 lanes/node) + relu + next projection ----
__global__ void k_flayer(const int* __restrict__ noff, const int* __restrict__ perm,
                         const float* __restrict__ g_in, float* __restrict__ g_out,
                         const float* __restrict__ dis, const float* __restrict__ bias,
                         const float* __restrict__ Wn, int n) {
    __shared__ float Ws[HDIM * HDIM];
    __shared__ float bs[HDIM];
    int t = threadIdx.x;
    if (t < HDIM * HDIM) Ws[t] = Wn[t];
    if (t < HDIM) bs[t] = bias[t];
    __syncthreads();
    int q = t >> 2, sub = t & 3;
    int i = blockIdx.x * 64 + q;
    if (i >= n) return;
    int s = noff[i], e = noff[i + 1];
    const float4* g4 = (const float4*)g_in;
    float a[HDIM] = {0, 0, 0, 0, 0, 0, 0, 0};
    int p = s + sub;
    // 2-way unrolled gather loop (independent chains for ILP)
    for (; p + 4 < e; p += 8) {
        int r0 = perm[p], r1 = perm[p + 4];
        float4 u0 = g4[(size_t)r0 * 2], v0 = g4[(size_t)r0 * 2 + 1];
        float4 u1 = g4[(size_t)r1 * 2], v1 = g4[(size_t)r1 * 2 + 1];
        a[0] += u0.x + u1.x; a[1] += u0.y + u1.y;
        a[2] += u0.z + u1.z; a[3] += u0.w + u1.w;
        a[4] += v0.x + v1.x; a[5] += v0.y + v1.y;
        a[6] += v0.z + v1.z; a[7] += v0.w + v1.w;
    }
    if (p < e) {
        int r = perm[p];
        float4 u = g4[(size_t)r * 2], v = g4[(size_t)r * 2 + 1];
        a[0] += u.x; a[1] += u.y; a[2] += u.z; a[3] += u.w;
        a[4] += v.x; a[5] += v.y; a[6] += v.z; a[7] += v.w;
    }
#pragma unroll
    for (int j = 0; j < HDIM; ++j) {
        a[j] += __shfl_xor(a[j], 1);
        a[j] += __shfl_xor(a[j], 2);
    }
    float di = dis[i];
    float4 s0 = g4[(size_t)i * 2], s1 = g4[(size_t)i * 2 + 1];   // self term
    float h[HDIM];
    h[0] = fmaxf(di * (a[0] + s0.x) + bs[0], 0.0f);
    h[1] = fmaxf(di * (a[1] + s0.y) + bs[1], 0.0f);
    h[2] = fmaxf(di * (a[2] + s0.z) + bs[2], 0.0f);
    h[3] = fmaxf(di * (a[3] + s0.w) + bs[3], 0.0f);
    h[4] = fmaxf(di * (a[4] + s1.x) + bs[4], 0.0f);
    h[5] = fmaxf(di * (a[5] + s1.y) + bs[5], 0.0f);
    h[6] = fmaxf(di * (a[6] + s1.z) + bs[6], 0.0f);
    h[7] = fmaxf(di * (a[7] + s1.w) + bs[7], 0.0f);
    // each lane computes 2 of the 8 next-layer outputs
    int j0 = sub * 2;
    float gn0 = 0.0f, gn1 = 0.0f;
#pragma unroll
    for (int k = 0; k < HDIM; ++k) {
        gn0 += h[k] * Ws[k * HDIM + j0];
        gn1 += h[k] * Ws[k * HDIM + j0 + 1];
    }
    ((float2*)g_out)[(size_t)i * 4 + sub] = make_float2(di * gn0, di * gn1);
}

// ---- fused last layer: gather + relu + proba head + per-block mean partial ----
__global__ void k_flayer3(const int* __restrict__ noff, const int* __restrict__ perm,
                          const float* __restrict__ g_in, const float* __restrict__ dis,
                          const float* __restrict__ b3, const float* __restrict__ Wp,
                          const float* __restrict__ bp, float* __restrict__ out,
                          float* __restrict__ partial, int n) {
    __shared__ float red[4][HDIM];
    int t = threadIdx.x;
    int q = t >> 2, sub = t & 3;
    int i = blockIdx.x * 64 + q;
    bool valid = i < n;
    const float4* g4 = (const float4*)g_in;
    float a[HDIM] = {0, 0, 0, 0, 0, 0, 0, 0};
    if (valid) {
        int s = noff[i], e = noff[i + 1];
        int p = s + sub;
        for (; p + 4 < e; p += 8) {
            int r0 = perm[p], r1 = perm[p + 4];
            float4 u0 = g4[(size_t)r0 * 2], v0 = g4[(size_t)r0 * 2 + 1];
            float4 u1 = g4[(size_t)r1 * 2], v1 = g4[(size_t)r1 * 2 + 1];
            a[0] += u0.x + u1.x; a[1] += u0.y + u1.y;
            a[2] += u0.z + u1.z; a[3] += u0.w + u1.w;
            a[4] += v0.x + v1.x; a[5] += v0.y + v1.y;
            a[6] += v0.z + v1.z; a[7] += v0.w + v1.w;
        }
        if (p < e) {
            int r = perm[p];
            float4 u = g4[(size_t)r * 2], v = g4[(size_t)r * 2 + 1];
            a[0] += u.x; a[1] += u.y; a[2] += u.z; a[3] += u.w;
            a[4] += v.x; a[5] += v.y; a[6] += v.z; a[7] += v.w;
        }
    }
#pragma unroll
    for (int j = 0; j < HDIM; ++j) {
        a[j] += __shfl_xor(a[j], 1);
        a[j] += __shfl_xor(a[j], 2);
    }
    float h[HDIM] = {0, 0, 0, 0, 0, 0, 0, 0};
    if (valid) {
        float di = dis[i];
        float4 s0 = g4[(size_t)i * 2], s1 = g4[(size_t)i * 2 + 1];
        h[0] = fmaxf(di * (a[0] + s0.x) + b3[0], 0.0f);
        h[1] = fmaxf(di * (a[1] + s0.y) + b3[1], 0.0f);
        h[2] = fmaxf(di * (a[2] + s0.z) + b3[2], 0.0f);
        h[3] = fmaxf(di * (a[3] + s0.w) + b3[3], 0.0f);
        h[4] = fmaxf(di * (a[4] + s1.x) + b3[4], 0.0f);
        h[5] = fmaxf(di * (a[5] + s1.y) + b3[5], 0.0f);
        h[6] = fmaxf(di * (a[6] + s1.z) + b3[6], 0.0f);
        h[7] = fmaxf(di * (a[7] + s1.w) + b3[7], 0.0f);
        if (sub == 0) {
            float p = bp[0];
#pragma unroll
            for (int j = 0; j < HDIM; ++j) p += h[j] * Wp[j];
            out[i] = p;
        }
    }
    // per-block mean partial: only sub==0 lanes contribute h
    int w = t >> 6, lane = t & 63;
#pragma unroll
    for (int j = 0; j < HDIM; ++j) {
        float sj = (sub == 0) ? h[j] : 0.0f;
#pragma unroll
        for (int o = 32; o > 0; o >>= 1) sj += __shfl_down(sj, o);
        if (lane == 0) red[w][j] = sj;
    }
    __syncthreads();
    if (t < HDIM)
        partial[(size_t)blockIdx.x * HDIM + t] =
            red[0][t] + red[1][t] + red[2][t] + red[3][t];
}

// ---- value head: reduce per-block partials ----
__global__ void k_value(const float* __restrict__ partial, int nblocks,
                        const float* __restrict__ Wv, const float* __restrict__ bv,
                        float* __restrict__ out, int n) {
    __shared__ float red[256];
    int t = threadIdx.x;
    int j = t & 7, c = t >> 3;               // 32 chunks x 8 components
    float v = 0.0f;
    for (int b = c; b < nblocks; b += 32) v += partial[(size_t)b * HDIM + j];
    red[t] = v;
    __syncthreads();
    for (int d = 128; d >= 8; d >>= 1) {
        if (t < d) red[t] += red[t + d];
        __syncthreads();
    }
    if (t == 0) {
        float val = bv[0];
        float inv_n = 1.0f / (float)n;
#pragma unroll
        for (int jj = 0; jj < HDIM; ++jj) val += (red[jj] * inv_n) * Wv[jj];
        out[n] = val;
    }
}

extern "C" void kernel_launch(void* const* d_in, const int* in_sizes, int n_in,
                              void* d_out, int out_size, void* d_ws, size_t ws_size,
                              hipStream_t stream) {
    const float* x  = (const float*)d_in[0];
    const int*   ei = (const int*)d_in[1];
    const float* W1 = (const float*)d_in[2];
    const float* b1 = (const float*)d_in[3];
    const float* W2 = (const float*)d_in[4];
    const float* b2 = (const float*)d_in[5];
    const float* W3 = (const float*)d_in[6];
    const float* b3 = (const float*)d_in[7];
    const float* Wp = (const float*)d_in[8];
    const float* bp = (const float*)d_in[9];
    const float* Wv = (const float*)d_in[10];
    const float* bv = (const float*)d_in[11];

    const int n = in_sizes[0] / 128;
    const int E = in_sizes[1] / 2;
    const int* row = ei;       // edge_index[0] = source
    const int* col = ei + E;   // edge_index[1] = target
    const int nbuck = (n + 255) >> 8;

    // workspace layout (4-byte units); ~58 MB total
    int*      bhist = (int*)d_ws;                   // 512
    int*      bbase = bhist + 512;                  // 512
    int*      bcur  = bhist + 1024;                 // 512 (ends 1536; pad to 6144)
    float*    dis   = (float*)(bhist + 6144);       // n
    int*      noff  = (int*)(dis + n);              // n+4 (padded)
    unsigned* bedge = (unsigned*)(noff + n + 4);    // E
    int*      perm  = (int*)(bedge + E);            // E
    float*    g_a   = (float*)(perm + E);           // n*8 (16B aligned)
    float*    g_b   = g_a + (size_t)n * HDIM;       // n*8
    float*    partial = g_b + (size_t)n * HDIM;     // ceil(n/64)*8

    dim3 blk(256);
    dim3 grid_n4(((size_t)n * 4 + 255) / 256);
    dim3 grid_e((E + 256 * EPB - 1) / (256 * EPB));
    dim3 grid_b(nbuck);
    dim3 grid_f((n + 63) / 64);                     // 64 nodes per 256-thr block
    const int nblocks3 = (n + 63) / 64;

    k_zero  <<<dim3((nbuck + 255) / 256), blk, 0, stream>>>(bhist, nbuck);
    k_bhist <<<grid_e, blk, 0, stream>>>(col, E, nbuck, bhist);
    k_bscan <<<dim3(1), dim3(MAXBUCK), 0, stream>>>(bhist, nbuck, bbase, bcur);
    k_bucket<<<grid_e, blk, 0, stream>>>(row, col, E, nbuck, bcur, bedge);
    k_place <<<grid_b, blk, 0, stream>>>(bbase, bedge, perm, noff, dis, n, E);
    k_proj1 <<<grid_n4, blk, 0, stream>>>(x, W1, dis, g_a, n);

    // layer 1 + 2 (fused gather+relu+proj)
    k_flayer<<<grid_f, blk, 0, stream>>>(noff, perm, g_a, g_b, dis, b1, W2, n);
    k_flayer<<<grid_f, blk, 0, stream>>>(noff, perm, g_b, g_a, dis, b2, W3, n);
    // layer 3 (fused gather+relu+heads)
    k_flayer3<<<grid_f, blk, 0, stream>>>(noff, perm, g_a, dis, b3, Wp, bp,
                                          (float*)d_out, partial, n);
    k_value <<<dim3(1), blk, 0, stream>>>(partial, nblocks3, Wv, bv,
                                          (float*)d_out, n);
}